// Round 3
// baseline (6547.048 us; speedup 1.0000x reference)
//
#include <hip/hip_runtime.h>
#include <math.h>

#define SRF 16000.0f
#define HOP 256
#define FRM 626
#define BB 8
#define TLEN 160000
#define NFRM (BB*FRM)
#define NCONV 262144
#define ACCLEN 161024

// ---------------- workspace layout (float offsets) ----------------
constexpr size_t oWIN   = 0;                       // 1024
constexpr size_t oTW    = oWIN + 1024;             // 1024 (512 complex)
constexpr size_t oDIAG  = oTW + 1024;              // 16 (unused this round)
constexpr size_t oAW    = oDIAG + 16;              // 513
constexpr size_t oMELFB = oAW + 513;               // 41040
constexpr size_t oWSQI  = oMELFB + 513*80;         // 161024
constexpr size_t oWHHT  = oWSQI + ACCLEN;          // 196608
constexpr size_t oWIHT  = oWHHT + 256*768;         // 61440
constexpr size_t oW0T   = oWIHT + 80*768;          // 10752
constexpr size_t oW1T   = oW0T + 21*512;           // 262144
constexpr size_t oW2T   = oW1T + 512*512;          // 262144
constexpr size_t oVTT   = oW2T + 512*512;          // 33280
constexpr size_t oNFT   = oVTT + 512*65;           // 33280
constexpr size_t oF0    = oNFT + 512*65;           // 5008
constexpr size_t oLOUD  = oF0 + NFRM;              // 5008
constexpr size_t oOQ    = oLOUD + NFRM;            // 5008
constexpr size_t oVT    = oOQ + NFRM;              // 325520
constexpr size_t oNF    = oVT + (size_t)NFRM*65;   // 325520
constexpr size_t oGLOT  = oNF + (size_t)NFRM*65;   // 1280000
constexpr size_t oNOISE = oGLOT + (size_t)BB*TLEN; // 1280000
constexpr size_t oACC   = oNOISE + (size_t)BB*TLEN;// 1288192
constexpr size_t oCONVA = oACC + (size_t)BB*ACCLEN;// 4718592
constexpr size_t oEND   = oCONVA + (size_t)9*NCONV*2;  // 10,297,137 floats = 41.2 MB
// overlays (lifetime-checked):
constexpr size_t oCONVB = oWSQI;                      // conv scratch; used only after k_dry
constexpr size_t oXP    = oGLOT;                      // GRU input; dead before noise/glottal/zacc
constexpr size_t oMEL = oCONVA;                       // dead before k_dry packs CONVA
constexpr size_t oHS  = oMEL + (size_t)NFRM*80;
constexpr size_t oZ   = oHS + (size_t)NFRM*256;       // ends < oCONVA + 8*NCONV*2 (ir slot)

// init task counts
constexpr long R_WIN=1024, R_TW=512, R_AW=513, R_MELFB=41040, R_WSQI=161024,
  R_WHHT=196608, R_WIHT=61440, R_W0T=10752, R_W1T=262144, R_W2T=262144,
  R_VTT=33280, R_NFT=33280, R_IR=NCONV;
constexpr long INIT_TOTAL = R_WIN+R_TW+R_AW+R_MELFB+R_WSQI+R_WHHT+R_WIHT+R_W0T+
  R_W1T+R_W2T+R_VTT+R_NFT+R_IR;

// ---------------- helpers ----------------
__device__ inline int mirror_idx(int j) {
  if (j < 0) j = -j;
  if (j >= TLEN) j = 2*TLEN - 2 - j;
  return j;
}
__device__ inline float sigm(float x) { return 1.0f/(1.0f + expf(-x)); }

__device__ inline float interpF(const float* v, int i) {
  float pos = ((float)i + 0.5f) * (626.0f/160000.0f) - 0.5f;
  pos = fminf(fmaxf(pos, 0.0f), 625.0f);
  int lo = (int)floorf(pos);
  int hi = min(lo + 1, 625);
  float w = pos - (float)lo;
  return v[lo]*(1.0f - w) + v[hi]*w;
}
__device__ inline float interp65(const float* v, int k) {
  float pos = ((float)k + 0.5f) * (65.0f/513.0f) - 0.5f;
  pos = fminf(fmaxf(pos, 0.0f), 64.0f);
  int lo = (int)floorf(pos);
  int hi = min(lo + 1, 64);
  float w = pos - (float)lo;
  return v[lo]*(1.0f - w) + v[hi]*w;
}

// radix-2 DIT FFT in LDS; input at bit-reversed positions; natural-order output.
template<int LOGN, int TS>
__device__ inline void fft_lds(float* re, float* im, const float* tw, int tid, int nthr, bool inv) {
  constexpr int N = 1 << LOGN;
  for (int s = 1; s <= LOGN; ++s) {
    const int half = 1 << (s-1);
    const int tstep = (N >> s) * TS;
    for (int bf = tid; bf < (N>>1); bf += nthr) {
      int jj = bf & (half-1);
      int i0 = ((bf >> (s-1)) << s) + jj;
      int i1 = i0 + half;
      int ti = jj * tstep;
      float wr = tw[2*ti], wi = tw[2*ti+1];
      if (inv) wi = -wi;
      float ur = re[i0], ui = im[i0];
      float vr = re[i1], vi = im[i1];
      float tr = vr*wr - vi*wi;
      float tci = vr*wi + vi*wr;
      re[i0] = ur + tr; im[i0] = ui + tci;
      re[i1] = ur - tr; im[i1] = ui - tci;
    }
    __syncthreads();
  }
}

// threefry2x32, canonical 20-round schedule
__device__ inline void threefry2x32(unsigned k0, unsigned k1, unsigned x0, unsigned x1,
                                    unsigned& o0, unsigned& o1) {
  unsigned ks2 = k0 ^ k1 ^ 0x1BD11BDAu;
  x0 += k0; x1 += k1;
#define TF_R(r) { x0 += x1; x1 = (x1<<(r)) | (x1>>(32-(r))); x1 ^= x0; }
  TF_R(13) TF_R(15) TF_R(26) TF_R(6)
  x0 += k1; x1 += ks2 + 1u;
  TF_R(17) TF_R(29) TF_R(16) TF_R(24)
  x0 += ks2; x1 += k0 + 2u;
  TF_R(13) TF_R(15) TF_R(26) TF_R(6)
  x0 += k0; x1 += k1 + 3u;
  TF_R(17) TF_R(29) TF_R(16) TF_R(24)
  x0 += k1; x1 += ks2 + 4u;
  TF_R(13) TF_R(15) TF_R(26) TF_R(6)
  x0 += ks2; x1 += k0 + 5u;
#undef TF_R
  o0 = x0; o1 = x1;
}

__device__ inline float erfinv_f(float x) { // XLA f32 ErfInv (Giles)
  float w = -log1pf(-x*x);
  float p;
  if (w < 5.0f) {
    w = w - 2.5f;
    p = 2.81022636e-08f;
    p = fmaf(p, w, 3.43273939e-07f);
    p = fmaf(p, w, -3.5233877e-06f);
    p = fmaf(p, w, -4.39150654e-06f);
    p = fmaf(p, w, 0.00021858087f);
    p = fmaf(p, w, -0.00125372503f);
    p = fmaf(p, w, -0.00417768164f);
    p = fmaf(p, w, 0.246640727f);
    p = fmaf(p, w, 1.50140941f);
  } else {
    w = sqrtf(w) - 3.0f;
    p = -0.000200214257f;
    p = fmaf(p, w, 0.000100950558f);
    p = fmaf(p, w, 0.00134934322f);
    p = fmaf(p, w, -0.00367342844f);
    p = fmaf(p, w, 0.00573950773f);
    p = fmaf(p, w, -0.0076224613f);
    p = fmaf(p, w, 0.00943887047f);
    p = fmaf(p, w, 1.00167406f);
    p = fmaf(p, w, 2.83297682f);
  }
  return p*x;
}
// JAX uniform(lo=-0.99999994, hi=1): u = max(lo, f*(hi-lo) + lo), f in [0,1)
__device__ inline float normal_from_bits(unsigned bits) {
  float f = __uint_as_float((bits >> 9) | 0x3F800000u) - 1.0f;
  float x = fmaxf(-0.99999994f, fmaf(f, 1.99999994f, -0.99999994f));
  return 1.41421356237f * erfinv_f(x);
}

__device__ inline double mel_fpt(int j) {
  double mmax = 2595.0 * log10(1.0 + 8000.0/700.0);
  return 700.0 * (pow(10.0, (mmax * (double)j / 81.0) / 2595.0) - 1.0);
}

// ---------------- init ----------------
__global__ void k_init(float* W, const float* whh, const float* wih, const float* w0,
                       const float* w1, const float* w2, const float* vtw, const float* nfw,
                       const float* ir) {
  long id = (long)blockIdx.x*256 + threadIdx.x;
  if (id < R_WIN) {
    double w = 0.5 - 0.5*cos(2.0*M_PI*(double)id/1024.0);
    W[oWIN+id] = (float)w; return;
  } id -= R_WIN;
  if (id < R_TW) {
    double a = -2.0*M_PI*(double)id/1024.0;
    W[oTW+2*id] = (float)cos(a); W[oTW+2*id+1] = (float)sin(a); return;
  } id -= R_TW;
  if (id < R_AW) {
    double fr = (double)id*(8000.0/512.0); double fsq = fr*fr;
    double num = 12194.217*12194.217*fsq*fsq;
    double den = (fsq+20.6*20.6)*(fsq+107.7*107.7)*(fsq+737.9*737.9)*sqrt(fsq+12194.217*12194.217) + 1e-8;
    W[oAW+id] = (float)(num/den); return;
  } id -= R_AW;
  if (id < R_MELFB) {
    int k = (int)(id/80), m = (int)(id%80);
    double fk = (double)k*(8000.0/512.0);
    double f0p = mel_fpt(m), f1p = mel_fpt(m+1), f2p = mel_fpt(m+2);
    double lower = (fk - f0p)/(f1p - f0p);
    double upper = (f2p - fk)/(f2p - f1p);
    double v = fmax(0.0, fmin(lower, upper));
    W[oMELFB+id] = (float)v; return;
  } id -= R_MELFB;
  if (id < R_WSQI) {
    int t = (int)id;
    int n1 = t/256; if (n1 > 625) n1 = 625;
    int n0t = t - 1023 + 255; int n0 = (n0t > 0) ? n0t/256 : 0;
    double s = 0.0;
    for (int n = n0; n <= n1; ++n) {
      int o = t - n*256;
      double wv = 0.5 - 0.5*cos(2.0*M_PI*(double)o/1024.0);
      s += wv*wv;
    }
    float sf = (float)s;
    W[oWSQI+t] = (sf > 1e-11f) ? (1.0f/sf) : 1.0f; return;
  } id -= R_WSQI;
  if (id < R_WHHT) { long k = id/768, g = id%768; W[oWHHT+id] = whh[g*256+k]; return; } id -= R_WHHT;
  if (id < R_WIHT) { long k = id/768, g = id%768; W[oWIHT+id] = wih[g*80+k];  return; } id -= R_WIHT;
  if (id < R_W0T)  { long d = id/512, j = id%512; W[oW0T+id] = w0[j*21+d];   return; } id -= R_W0T;
  if (id < R_W1T)  { long k = id/512, j = id%512; W[oW1T+id] = w1[j*512+k];  return; } id -= R_W1T;
  if (id < R_W2T)  { long k = id/512, j = id%512; W[oW2T+id] = w2[j*512+k];  return; } id -= R_W2T;
  if (id < R_VTT)  { long k = id/65,  m = id%65;  W[oVTT+id] = vtw[m*512+k]; return; } id -= R_VTT;
  if (id < R_NFT)  { long k = id/65,  m = id%65;  W[oNFT+id] = nfw[m*512+k]; return; } id -= R_NFT;
  if (id < R_IR) {
    size_t base = oCONVA + 2*((size_t)8*NCONV + id);
    W[base] = (id < 8000) ? ir[id] : 0.0f; W[base+1] = 0.0f; return;
  }
}

__global__ void k_zacc(float* W) {
  size_t id = (size_t)blockIdx.x*256 + threadIdx.x;
  if (id < (size_t)BB*ACCLEN) W[oACC+id] = 0.0f;
}

// ---------------- f0 via direct linear autocorrelation ----------------
__global__ __launch_bounds__(320) void k_f0(const float* audio, float* W) {
  int blk = blockIdx.x; int b = blk/FRM, f = blk%FRM; int tid = threadIdx.x;
  __shared__ float fr[1024];
  __shared__ float val[304];
  __shared__ float psum[320];
  const float* arow = audio + (size_t)b*TLEN;
  for (int i = tid; i < 1024; i += 320) fr[i] = arow[mirror_idx(f*256 + i - 512)];
  __syncthreads();
  float p = 0.f;
  for (int i = tid; i < 1024; i += 320) p += fr[i]*fr[i];
  psum[tid] = p;
  if (tid < 304) {
    int lag = 16 + tid; float s = 0.f;
    for (int t0 = 0; t0 < 1024; ++t0) if (t0 + lag < 1024) s += fr[t0]*fr[t0+lag];
    val[tid] = s;
  }
  __syncthreads();
  if (tid == 0) {
    float ac0 = 0.f;
    for (int i = 0; i < 320; ++i) ac0 += psum[i];
    float inv = 1.0f/(ac0 + 1e-8f);
    float best = -1e30f; int bi = 0;
    for (int i = 0; i < 304; ++i) { float v = val[i]*inv; if (v > best) { best = v; bi = i; } }
    float f0v = (best < 0.3f) ? 0.0f : (SRF/(float)(bi + 16));
    W[oF0 + blk] = f0v;
  }
}

// ---------------- STFT of audio + loud + mel ----------------
__global__ __launch_bounds__(256) void k_stft_mel(const float* audio, float* W) {
  int blk = blockIdx.x; int b = blk/FRM, f = blk%FRM; int tid = threadIdx.x;
  __shared__ float re[1024], im[1024], spec[513];
  __shared__ float redbuf[4];
  const float* arow = audio + (size_t)b*TLEN;
  const float* tw = W + oTW;
  for (int i = tid; i < 1024; i += 256) {
    float v = arow[mirror_idx(f*256 + i - 512)] * W[oWIN + i];
    int pos = __brev((unsigned)i) >> 22;
    re[pos] = v; im[pos] = 0.f;
  }
  __syncthreads();
  fft_lds<10,1>(re, im, tw, tid, 256, false);
  for (int k = tid; k < 513; k += 256) spec[k] = re[k]*re[k] + im[k]*im[k];
  __syncthreads();
  float part = 0.f;
  for (int k = tid; k < 513; k += 256) part += (spec[k] + 1e-8f) * W[oAW + k];
  for (int off = 32; off; off >>= 1) part += __shfl_down(part, off, 64);
  if ((tid & 63) == 0) redbuf[tid >> 6] = part;
  __syncthreads();
  if (tid == 0) {
    float s = redbuf[0]+redbuf[1]+redbuf[2]+redbuf[3];
    W[oLOUD + blk] = 10.0f * log10f(s / 513.0f);
  }
  for (int m = tid; m < 80; m += 256) {
    float s = 0.f;
    for (int k = 0; k < 513; ++k) s += spec[k]*W[oMELFB + (size_t)k*80 + m];
    W[oMEL + (size_t)blk*80 + m] = logf(s + 1e-5f);
  }
}

// ---------------- mel normalization over time ----------------
__global__ void k_melnorm(float* W) {
  int id = blockIdx.x*256 + threadIdx.x;
  if (id >= BB*80) return;
  int b = id/80, m = id%80;
  double s = 0.0, ss = 0.0;
  for (int f = 0; f < FRM; ++f) {
    double v = W[oMEL + ((size_t)b*FRM + f)*80 + m];
    s += v; ss += v*v;
  }
  double mean = s/FRM;
  double var = ss/FRM - mean*mean;
  float mu = (float)mean;
  float rstd = (float)(1.0/sqrt(var + 1e-5));
  for (int f = 0; f < FRM; ++f) {
    size_t idx = oMEL + ((size_t)b*FRM + f)*80 + m;
    W[idx] = (W[idx] - mu)*rstd;
  }
}

// ---------------- GRU input precompute ----------------
__global__ void k_xp(float* W, const float* bih) {
  size_t id = (size_t)blockIdx.x*256 + threadIdx.x;
  if (id >= (size_t)NFRM*768) return;
  int g = (int)(id % 768);
  size_t q = id / 768;
  const float* mrow = W + oMEL + q*80;
  float acc = bih[g];
  for (int k = 0; k < 80; ++k) acc = fmaf(mrow[k], W[oWIHT + (size_t)k*768 + g], acc);
  W[oXP + q*768 + g] = acc;
}

// ---------------- sequential GRU ----------------
__global__ __launch_bounds__(768) void k_gru(float* W, const float* bhh) {
  int b = blockIdx.x; int g = threadIdx.x;
  __shared__ float hsh[256];
  __shared__ float ghs[768];
  if (g < 256) hsh[g] = 0.f;
  __syncthreads();
  float bg = bhh[g];
  const float* wT = W + oWHHT;
  for (int t = 0; t < FRM; ++t) {
    float acc = 0.f;
    #pragma unroll 8
    for (int k = 0; k < 256; ++k) acc = fmaf(hsh[k], wT[(size_t)k*768 + g], acc);
    ghs[g] = acc + bg;
    __syncthreads();
    if (g < 256) {
      const float* xrow = W + oXP + ((size_t)b*FRM + t)*768;
      float r = sigm(xrow[g] + ghs[g]);
      float z = sigm(xrow[256+g] + ghs[256+g]);
      float n = tanhf(xrow[512+g] + r*ghs[512+g]);
      float h = (1.0f - z)*n + z*hsh[g];
      hsh[g] = h;
      W[oHS + ((size_t)b*FRM + t)*256 + g] = h;
    }
    __syncthreads();
  }
}

// ---------------- projection ----------------
__global__ void k_proj(float* W, const float* projw, const float* projb) {
  size_t id = (size_t)blockIdx.x*256 + threadIdx.x;
  if (id >= (size_t)NFRM*16) return;
  int zi = (int)(id % 16);
  size_t q = id / 16;
  const float* hrow = W + oHS + q*256;
  float acc = projb[zi];
  for (int k = 0; k < 256; ++k) acc = fmaf(hrow[k], projw[zi*256 + k], acc);
  W[oZ + q*16 + zi] = acc;
}

// ---------------- MLP + heads ----------------
__device__ inline void ln_lrelu(float acc[8], float gj, float ej, float out[8][512],
                                float wred[8][8][2], float stat[8][2],
                                int tid, int lane, int wv, int j) {
  #pragma unroll
  for (int i = 0; i < 8; ++i) {
    float s = acc[i], ss = acc[i]*acc[i];
    for (int off = 32; off; off >>= 1) { s += __shfl_down(s, off, 64); ss += __shfl_down(ss, off, 64); }
    if (lane == 0) { wred[i][wv][0] = s; wred[i][wv][1] = ss; }
  }
  __syncthreads();
  if (tid < 8) {
    float s = 0.f, ss = 0.f;
    #pragma unroll
    for (int w = 0; w < 8; ++w) { s += wred[tid][w][0]; ss += wred[tid][w][1]; }
    float mean = s/512.0f;
    float var = ss/512.0f - mean*mean;
    stat[tid][0] = mean;
    stat[tid][1] = 1.0f/sqrtf(var + 1e-5f);
  }
  __syncthreads();
  #pragma unroll
  for (int i = 0; i < 8; ++i) {
    float v = (acc[i] - stat[i][0])*stat[i][1]*gj + ej;
    out[i][j] = (v >= 0.f) ? v : 0.1f*v;
  }
}

__global__ __launch_bounds__(512) void k_mlp(float* W, const float* gender, const float* age,
    const float* b0, const float* g0, const float* e0,
    const float* b1, const float* g1, const float* e1,
    const float* b2, const float* g2, const float* e2,
    const float* oqw, const float* oqb, const float* vtb, const float* nfb) {
  __shared__ float in0[8][21];
  __shared__ float actA[8][512];
  __shared__ float actB[8][512];
  __shared__ float wred[8][8][2];
  __shared__ float stat[8][2];
  int tid = threadIdx.x; int q0 = blockIdx.x*8;
  if (tid < 168) {
    int i = tid/21, d = tid%21; int q = q0 + i; int b = q/FRM;
    float v;
    if (d < 16) v = W[oZ + (size_t)q*16 + d];
    else if (d == 16) v = (logf(W[oF0 + q] + 1e-5f) - 4.0f)*0.25f;
    else if (d == 17) v = W[oLOUD + q]/100.0f + 1.0f;
    else if (d == 18) v = gender[b*2];
    else if (d == 19) v = gender[b*2 + 1];
    else v = age[b];
    in0[i][d] = v;
  }
  __syncthreads();
  int j = tid, lane = tid & 63, wv = tid >> 6;
  float acc[8];
  #pragma unroll
  for (int i = 0; i < 8; ++i) acc[i] = b0[j];
  for (int d = 0; d < 21; ++d) {
    float w = W[oW0T + (size_t)d*512 + j];
    #pragma unroll
    for (int i = 0; i < 8; ++i) acc[i] = fmaf(in0[i][d], w, acc[i]);
  }
  ln_lrelu(acc, g0[j], e0[j], actA, wred, stat, tid, lane, wv, j);
  __syncthreads();
  #pragma unroll
  for (int i = 0; i < 8; ++i) acc[i] = b1[j];
  for (int k = 0; k < 512; ++k) {
    float w = W[oW1T + (size_t)k*512 + j];
    #pragma unroll
    for (int i = 0; i < 8; ++i) acc[i] = fmaf(actA[i][k], w, acc[i]);
  }
  ln_lrelu(acc, g1[j], e1[j], actB, wred, stat, tid, lane, wv, j);
  __syncthreads();
  #pragma unroll
  for (int i = 0; i < 8; ++i) acc[i] = b2[j];
  for (int k = 0; k < 512; ++k) {
    float w = W[oW2T + (size_t)k*512 + j];
    #pragma unroll
    for (int i = 0; i < 8; ++i) acc[i] = fmaf(actB[i][k], w, acc[i]);
  }
  ln_lrelu(acc, g2[j], e2[j], actA, wred, stat, tid, lane, wv, j);
  __syncthreads();
  for (int x = tid; x < 520; x += 512) {
    int i = x/65, m = x%65;
    float a = vtb[m], a2 = nfb[m];
    for (int k = 0; k < 512; ++k) {
      float h = actA[i][k];
      a  = fmaf(h, W[oVTT + (size_t)k*65 + m], a);
      a2 = fmaf(h, W[oNFT + (size_t)k*65 + m], a2);
    }
    W[oVT + (size_t)(q0+i)*65 + m] = sigm(a);
    W[oNF + (size_t)(q0+i)*65 + m] = sigm(a2);
  }
  if (tid < 8) {
    float a = oqb[0];
    for (int k = 0; k < 512; ++k) a = fmaf(actA[tid][k], oqw[k], a);
    W[oOQ + q0 + tid] = sigm(a);
  }
}

// ---------------- noise: JAX threefry PARTITIONABLE path, key (0,42) ----------------
// _threefry_random_bits_partitionable: counters = iota_2x32_shape (hi,lo of flat idx);
// bits1, bits2 = threefry2x32(key, hi, lo); for bit_width 32:
// bits = convert_element_type(bits1 ^ bits2, uint32)  <-- XOR of both output words
__global__ void k_noise(float* W) {
  int p = blockIdx.x*256 + threadIdx.x;
  if (p >= BB*TLEN) return;
  unsigned o0, o1;
  threefry2x32(0u, 42u, 0u, (unsigned)p, o0, o1);
  W[oNOISE + p] = normal_from_bits(o0 ^ o1);
}

// ---------------- glottal ----------------
__global__ __launch_bounds__(256) void k_glottal(float* W) {
  int b = blockIdx.x; int tid = threadIdx.x;
  __shared__ float wsums[4];
  __shared__ float gbuf[256];
  __shared__ double carry_sh;
  __shared__ float gprev_sh, ctot_sh;
  const float* f0r = W + oF0 + (size_t)b*FRM;
  const float* oqr = W + oOQ + (size_t)b*FRM;
  float* grow = W + oGLOT + (size_t)b*TLEN;
  if (tid == 0) { carry_sh = 0.0; gprev_sh = 0.f; }
  __syncthreads();
  int lane = tid & 63, wv = tid >> 6;
  for (int c = 0; c < TLEN/256; ++c) {
    int i = c*256 + tid;
    float v = interpF(f0r, i) / SRF;
    float s = v;
    #pragma unroll
    for (int off = 1; off < 64; off <<= 1) {
      float o = __shfl_up(s, off, 64);
      if (lane >= off) s += o;
    }
    if (lane == 63) wsums[wv] = s;
    __syncthreads();
    float wpre = 0.f;
    for (int wwi = 0; wwi < wv; ++wwi) wpre += wsums[wwi];
    float ph = (float)(carry_sh + (double)(wpre + s));
    float p = ph - floorf(ph);
    float oqu = interpF(oqr, i);
    float oqc = fminf(fmaxf(oqu, 0.1f), 0.9f);
    float pulse = 0.5f*(1.0f - cosf(3.14159265358979f * p / (oqc + 1e-8f)));
    float gs = 1.0f/(1.0f + expf(-(oqc - p)*100.0f));
    float g = pulse*gs;
    gbuf[tid] = g;
    if (tid == 255) ctot_sh = wpre + s;
    __syncthreads();
    float gl = (tid == 0) ? gprev_sh : gbuf[tid-1];
    grow[i] = (i == 0) ? 0.f : (g - gl);
    __syncthreads();
    if (tid == 0) { carry_sh += (double)ctot_sh; gprev_sh = gbuf[255]; }
    __syncthreads();
  }
}

// ---------------- fused STFT->filter->ISTFT OLA ----------------
__global__ __launch_bounds__(256) void k_filtsynth(float* W) {
  int blk = blockIdx.x; int b = blk/FRM, f = blk%FRM; int tid = threadIdx.x;
  __shared__ float reG[1024], imG[1024], reN[1024], imN[1024];
  __shared__ float fvt[65], fnf[65];
  const float* grow = W + oGLOT + (size_t)b*TLEN;
  const float* nrow = W + oNOISE + (size_t)b*TLEN;
  const float* tw = W + oTW;
  for (int i = tid; i < 1024; i += 256) {
    int si = mirror_idx(f*256 + i - 512);
    float wv = W[oWIN + i];
    int pos = __brev((unsigned)i) >> 22;
    reG[pos] = grow[si]*wv; imG[pos] = 0.f;
    reN[pos] = nrow[si]*wv; imN[pos] = 0.f;
  }
  if (tid < 65) {
    fvt[tid] = W[oVT + ((size_t)b*FRM + f)*65 + tid];
    fnf[tid] = W[oNF + ((size_t)b*FRM + f)*65 + tid];
  }
  __syncthreads();
  fft_lds<10,1>(reG, imG, tw, tid, 256, false);
  fft_lds<10,1>(reN, imN, tw, tid, 256, false);
  for (int k = tid; k < 1024; k += 256) {
    int kp = min(k, 1024 - k);
    float fv = interp65(fvt, kp);
    float fn = interp65(fnf, kp);
    reG[k] = reG[k]*fv + reN[k]*fn;
    imG[k] = imG[k]*fv + imN[k]*fn;
  }
  __syncthreads();
  for (int i = tid; i < 1024; i += 256) {
    int jj = __brev((unsigned)i) >> 22;
    if (jj > i) {
      float tr = reG[i]; reG[i] = reG[jj]; reG[jj] = tr;
      float ti = imG[i]; imG[i] = imG[jj]; imG[jj] = ti;
    }
  }
  __syncthreads();
  fft_lds<10,1>(reG, imG, tw, tid, 256, true);
  float* arow = W + oACC + (size_t)b*ACCLEN + (size_t)f*256;
  for (int i = tid; i < 1024; i += 256) {
    float xv = reG[i]*(1.0f/1024.0f)*W[oWIN + i];
    atomicAdd(arow + i, xv);
  }
}

// ---------------- dry ----------------
__global__ void k_dry(float* W, float* dout) {
  size_t id = (size_t)blockIdx.x*256 + threadIdx.x;
  if (id >= (size_t)BB*NCONV) return;
  int b = (int)(id / NCONV);
  int n = (int)(id % NCONV);
  float dv = 0.f;
  if (n < TLEN) {
    float val = W[oACC + (size_t)b*ACCLEN + 512 + n] * W[oWSQI + 512 + n];
    const float* lrow = W + oLOUD + (size_t)b*FRM;
    float pos = ((float)n + 0.5f) * (626.0f/160000.0f) - 0.5f;
    pos = fminf(fmaxf(pos, 0.0f), 625.0f);
    int lo = (int)floorf(pos);
    int hi = min(lo + 1, 625);
    float w = pos - (float)lo;
    float a0 = exp10f(lrow[lo]*0.05f);
    float a1 = exp10f(lrow[hi]*0.05f);
    float ampu = a0*(1.0f - w) + a1*w;
    dv = val*ampu;
    dout[(size_t)BB*TLEN + (size_t)b*TLEN + n] = dv;
  }
  W[oCONVA + 2*id] = dv;
  W[oCONVA + 2*id + 1] = 0.f;
}

// ---------------- four-step FFT (N = 512*512) ----------------
__global__ __launch_bounds__(256) void k_conv_f1(const float* in, float* out, const float* tw) {
  int blk = blockIdx.x; int t = blk >> 9; int bcol = blk & 511; int tid = threadIdx.x;
  __shared__ float re[512], im[512];
  const float* src = in + (size_t)t*NCONV*2;
  for (int a = tid; a < 512; a += 256) {
    int pos = __brev((unsigned)a) >> 23;
    size_t idx = 2*((size_t)a*512 + bcol);
    re[pos] = src[idx]; im[pos] = src[idx+1];
  }
  __syncthreads();
  fft_lds<9,2>(re, im, tw, tid, 256, false);
  float* dst = out + (size_t)t*NCONV*2 + (size_t)bcol*512*2;
  for (int k1 = tid; k1 < 512; k1 += 256) {
    long bk = (long)bcol*k1;
    float ang = -6.283185307179586f * ((float)bk * (1.0f/262144.0f));
    float sv, cv; sincosf(ang, &sv, &cv);
    float r = re[k1], iv = im[k1];
    dst[2*k1]   = r*cv - iv*sv;
    dst[2*k1+1] = r*sv + iv*cv;
  }
}

__global__ __launch_bounds__(256) void k_conv_f2(const float* in, float* out, const float* tw) {
  int blk = blockIdx.x; int t = blk >> 9; int k1 = blk & 511; int tid = threadIdx.x;
  __shared__ float re[512], im[512];
  const float* src = in + (size_t)t*NCONV*2;
  for (int bb2 = tid; bb2 < 512; bb2 += 256) {
    int pos = __brev((unsigned)bb2) >> 23;
    size_t idx = 2*((size_t)bb2*512 + k1);
    re[pos] = src[idx]; im[pos] = src[idx+1];
  }
  __syncthreads();
  fft_lds<9,2>(re, im, tw, tid, 256, false);
  float* dst = out + (size_t)t*NCONV*2;
  for (int k2 = tid; k2 < 512; k2 += 256) {
    size_t idx = 2*((size_t)k1 + 512*(size_t)k2);
    dst[idx] = re[k2]; dst[idx+1] = im[k2];
  }
}

__global__ void k_mul(float* W) {
  size_t id = (size_t)blockIdx.x*256 + threadIdx.x;
  if (id >= (size_t)BB*NCONV) return;
  size_t k = id % NCONV;
  float* A = W + oCONVA;
  float ar = A[2*id], ai = A[2*id+1];
  size_t ic = 2*((size_t)8*NCONV + k);
  float cr = A[ic], ci = A[ic+1];
  float pr = ar*cr - ai*ci;
  float pi = ar*ci + ai*cr;
  A[2*id] = pr;
  A[2*id+1] = -pi;
}

__global__ void k_wet(const float* W, float* dout) {
  size_t id = (size_t)blockIdx.x*256 + threadIdx.x;
  if (id >= (size_t)BB*TLEN) return;
  size_t b = id / TLEN, n = id % TLEN;
  dout[id] = W[oCONVA + 2*(b*NCONV + n)] * (1.0f/262144.0f);
}

// ---------------- launch ----------------
extern "C" void kernel_launch(void* const* d_in, const int* in_sizes, int n_in,
                              void* d_out, int out_size, void* d_ws, size_t ws_size,
                              hipStream_t stream) {
  (void)in_sizes; (void)n_in; (void)out_size; (void)ws_size;
  const float* audio  = (const float*)d_in[0];
  const float* gender = (const float*)d_in[1];
  const float* age    = (const float*)d_in[2];
  const float* wih    = (const float*)d_in[3];
  const float* whh    = (const float*)d_in[4];
  const float* bih    = (const float*)d_in[5];
  const float* bhh    = (const float*)d_in[6];
  const float* projw  = (const float*)d_in[7];
  const float* projb  = (const float*)d_in[8];
  const float* w0     = (const float*)d_in[9];
  const float* b0     = (const float*)d_in[10];
  const float* g0     = (const float*)d_in[11];
  const float* e0     = (const float*)d_in[12];
  const float* w1     = (const float*)d_in[13];
  const float* b1     = (const float*)d_in[14];
  const float* g1     = (const float*)d_in[15];
  const float* e1     = (const float*)d_in[16];
  const float* w2     = (const float*)d_in[17];
  const float* b2     = (const float*)d_in[18];
  const float* g2     = (const float*)d_in[19];
  const float* e2     = (const float*)d_in[20];
  const float* oqw    = (const float*)d_in[21];
  const float* oqb    = (const float*)d_in[22];
  const float* vtw    = (const float*)d_in[23];
  const float* vtb    = (const float*)d_in[24];
  const float* nfw    = (const float*)d_in[25];
  const float* nfb    = (const float*)d_in[26];
  const float* ir     = (const float*)d_in[27];
  float* W = (float*)d_ws;
  float* dout = (float*)d_out;

  k_init<<<(int)((INIT_TOTAL + 255)/256), 256, 0, stream>>>(W, whh, wih, w0, w1, w2, vtw, nfw, ir);
  k_f0<<<NFRM, 320, 0, stream>>>(audio, W);
  k_stft_mel<<<NFRM, 256, 0, stream>>>(audio, W);
  k_melnorm<<<3, 256, 0, stream>>>(W);
  k_xp<<<(int)(((size_t)NFRM*768 + 255)/256), 256, 0, stream>>>(W, bih);
  k_gru<<<BB, 768, 0, stream>>>(W, bhh);
  k_proj<<<(int)(((size_t)NFRM*16 + 255)/256), 256, 0, stream>>>(W, projw, projb);
  k_mlp<<<NFRM/8, 512, 0, stream>>>(W, gender, age, b0, g0, e0, b1, g1, e1, b2, g2, e2, oqw, oqb, vtb, nfb);
  k_zacc<<<(int)(((size_t)BB*ACCLEN + 255)/256), 256, 0, stream>>>(W);
  k_noise<<<(BB*TLEN + 255)/256, 256, 0, stream>>>(W);
  k_glottal<<<BB, 256, 0, stream>>>(W);
  k_filtsynth<<<NFRM, 256, 0, stream>>>(W);
  k_dry<<<(int)(((size_t)BB*NCONV + 255)/256), 256, 0, stream>>>(W, dout);
  k_conv_f1<<<9*512, 256, 0, stream>>>(W + oCONVA, W + oCONVB, W + oTW);
  k_conv_f2<<<9*512, 256, 0, stream>>>(W + oCONVB, W + oCONVA, W + oTW);
  k_mul<<<(int)(((size_t)BB*NCONV + 255)/256), 256, 0, stream>>>(W);
  k_conv_f1<<<8*512, 256, 0, stream>>>(W + oCONVA, W + oCONVB, W + oTW);
  k_conv_f2<<<8*512, 256, 0, stream>>>(W + oCONVB, W + oCONVA, W + oTW);
  k_wet<<<(int)(((size_t)BB*TLEN + 255)/256), 256, 0, stream>>>(W, dout);
}

// Round 4
// 3371.543 us; speedup vs baseline: 1.9419x; 1.9419x over previous
//
#include <hip/hip_runtime.h>
#include <math.h>

#define SRF 16000.0f
#define HOP 256
#define FRM 626
#define BB 8
#define TLEN 160000
#define NFRM (BB*FRM)
#define NCONV 262144
#define ACCLEN 161024

// ---------------- workspace layout (float offsets) ----------------
constexpr size_t oWIN   = 0;                       // 1024
constexpr size_t oTW    = oWIN + 1024;             // 1024 (512 complex)
constexpr size_t oDIAG  = oTW + 1024;              // 16 (unused)
constexpr size_t oAW    = oDIAG + 16;              // 513
constexpr size_t oMELFB = oAW + 513;               // 41040
constexpr size_t oWSQI  = oMELFB + 513*80;         // 161024
constexpr size_t oWHHT  = oWSQI + ACCLEN;          // 196608 (UNUSED now; gap kept)
constexpr size_t oWIHT  = oWHHT + 256*768;         // 61440
constexpr size_t oW0T   = oWIHT + 80*768;          // 10752
constexpr size_t oW1T   = oW0T + 21*512;           // 262144
constexpr size_t oW2T   = oW1T + 512*512;          // 262144
constexpr size_t oVTT   = oW2T + 512*512;          // 33280
constexpr size_t oNFT   = oVTT + 512*65;           // 33280
constexpr size_t oF0    = oNFT + 512*65;           // 5008
constexpr size_t oLOUD  = oF0 + NFRM;              // 5008
constexpr size_t oOQ    = oLOUD + NFRM;            // 5008
constexpr size_t oVT    = oOQ + NFRM;              // 325520
constexpr size_t oNF    = oVT + (size_t)NFRM*65;   // 325520
constexpr size_t oGLOT  = oNF + (size_t)NFRM*65;   // 1280000
constexpr size_t oNOISE = oGLOT + (size_t)BB*TLEN; // 1280000
constexpr size_t oACC   = oNOISE + (size_t)BB*TLEN;// 1288192
constexpr size_t oCONVA = oACC + (size_t)BB*ACCLEN;// 4718592
constexpr size_t oEND   = oCONVA + (size_t)9*NCONV*2;
// overlays (lifetime-checked):
constexpr size_t oCONVB = oWSQI;                      // conv scratch; used only after k_dry
constexpr size_t oXP    = oGLOT;                      // GRU input; dead before noise/glottal/zacc
constexpr size_t oMEL = oCONVA;                       // dead before k_dry packs CONVA
constexpr size_t oHS  = oMEL + (size_t)NFRM*80;
constexpr size_t oZ   = oHS + (size_t)NFRM*256;

// init task counts (WHHT transpose removed — MFMA GRU reads whh directly)
constexpr long R_WIN=1024, R_TW=512, R_AW=513, R_MELFB=41040, R_WSQI=161024,
  R_WIHT=61440, R_W0T=10752, R_W1T=262144, R_W2T=262144,
  R_VTT=33280, R_NFT=33280, R_IR=NCONV;
constexpr long INIT_TOTAL = R_WIN+R_TW+R_AW+R_MELFB+R_WSQI+R_WIHT+R_W0T+
  R_W1T+R_W2T+R_VTT+R_NFT+R_IR;

typedef float f32x4 __attribute__((ext_vector_type(4)));
typedef __bf16 bf16x8 __attribute__((ext_vector_type(8)));
typedef short short8 __attribute__((ext_vector_type(8)));
#define MFMA_BF16 __builtin_amdgcn_mfma_f32_16x16x32_bf16

// ---------------- helpers ----------------
__device__ inline int mirror_idx(int j) {
  if (j < 0) j = -j;
  if (j >= TLEN) j = 2*TLEN - 2 - j;
  return j;
}
__device__ inline float sigm(float x) { return 1.0f/(1.0f + expf(-x)); }
__device__ inline unsigned short f2bf(float x) {
  unsigned u = __float_as_uint(x);
  return (unsigned short)((u + 0x7FFFu + ((u >> 16) & 1u)) >> 16);
}
__device__ inline float bf2f(unsigned short v) {
  return __uint_as_float(((unsigned)v) << 16);
}

__device__ inline float interpF(const float* v, int i) {
  float pos = ((float)i + 0.5f) * (626.0f/160000.0f) - 0.5f;
  pos = fminf(fmaxf(pos, 0.0f), 625.0f);
  int lo = (int)floorf(pos);
  int hi = min(lo + 1, 625);
  float w = pos - (float)lo;
  return v[lo]*(1.0f - w) + v[hi]*w;
}
__device__ inline float interp65(const float* v, int k) {
  float pos = ((float)k + 0.5f) * (65.0f/513.0f) - 0.5f;
  pos = fminf(fmaxf(pos, 0.0f), 64.0f);
  int lo = (int)floorf(pos);
  int hi = min(lo + 1, 64);
  float w = pos - (float)lo;
  return v[lo]*(1.0f - w) + v[hi]*w;
}

// radix-2 DIT FFT in LDS; input at bit-reversed positions; natural-order output.
template<int LOGN, int TS>
__device__ inline void fft_lds(float* re, float* im, const float* tw, int tid, int nthr, bool inv) {
  constexpr int N = 1 << LOGN;
  for (int s = 1; s <= LOGN; ++s) {
    const int half = 1 << (s-1);
    const int tstep = (N >> s) * TS;
    for (int bf = tid; bf < (N>>1); bf += nthr) {
      int jj = bf & (half-1);
      int i0 = ((bf >> (s-1)) << s) + jj;
      int i1 = i0 + half;
      int ti = jj * tstep;
      float wr = tw[2*ti], wi = tw[2*ti+1];
      if (inv) wi = -wi;
      float ur = re[i0], ui = im[i0];
      float vr = re[i1], vi = im[i1];
      float tr = vr*wr - vi*wi;
      float tci = vr*wi + vi*wr;
      re[i0] = ur + tr; im[i0] = ui + tci;
      re[i1] = ur - tr; im[i1] = ui - tci;
    }
    __syncthreads();
  }
}

// threefry2x32, canonical 20-round schedule
__device__ inline void threefry2x32(unsigned k0, unsigned k1, unsigned x0, unsigned x1,
                                    unsigned& o0, unsigned& o1) {
  unsigned ks2 = k0 ^ k1 ^ 0x1BD11BDAu;
  x0 += k0; x1 += k1;
#define TF_R(r) { x0 += x1; x1 = (x1<<(r)) | (x1>>(32-(r))); x1 ^= x0; }
  TF_R(13) TF_R(15) TF_R(26) TF_R(6)
  x0 += k1; x1 += ks2 + 1u;
  TF_R(17) TF_R(29) TF_R(16) TF_R(24)
  x0 += ks2; x1 += k0 + 2u;
  TF_R(13) TF_R(15) TF_R(26) TF_R(6)
  x0 += k0; x1 += k1 + 3u;
  TF_R(17) TF_R(29) TF_R(16) TF_R(24)
  x0 += k1; x1 += ks2 + 4u;
  TF_R(13) TF_R(15) TF_R(26) TF_R(6)
  x0 += ks2; x1 += k0 + 5u;
#undef TF_R
  o0 = x0; o1 = x1;
}

__device__ inline float erfinv_f(float x) { // XLA f32 ErfInv (Giles)
  float w = -log1pf(-x*x);
  float p;
  if (w < 5.0f) {
    w = w - 2.5f;
    p = 2.81022636e-08f;
    p = fmaf(p, w, 3.43273939e-07f);
    p = fmaf(p, w, -3.5233877e-06f);
    p = fmaf(p, w, -4.39150654e-06f);
    p = fmaf(p, w, 0.00021858087f);
    p = fmaf(p, w, -0.00125372503f);
    p = fmaf(p, w, -0.00417768164f);
    p = fmaf(p, w, 0.246640727f);
    p = fmaf(p, w, 1.50140941f);
  } else {
    w = sqrtf(w) - 3.0f;
    p = -0.000200214257f;
    p = fmaf(p, w, 0.000100950558f);
    p = fmaf(p, w, 0.00134934322f);
    p = fmaf(p, w, -0.00367342844f);
    p = fmaf(p, w, 0.00573950773f);
    p = fmaf(p, w, -0.0076224613f);
    p = fmaf(p, w, 0.00943887047f);
    p = fmaf(p, w, 1.00167406f);
    p = fmaf(p, w, 2.83297682f);
  }
  return p*x;
}
__device__ inline float normal_from_bits(unsigned bits) {
  float f = __uint_as_float((bits >> 9) | 0x3F800000u) - 1.0f;
  float x = fmaxf(-0.99999994f, fmaf(f, 1.99999994f, -0.99999994f));
  return 1.41421356237f * erfinv_f(x);
}

__device__ inline double mel_fpt(int j) {
  double mmax = 2595.0 * log10(1.0 + 8000.0/700.0);
  return 700.0 * (pow(10.0, (mmax * (double)j / 81.0) / 2595.0) - 1.0);
}

// ---------------- init ----------------
__global__ void k_init(float* W, const float* wih, const float* w0,
                       const float* w1, const float* w2, const float* vtw, const float* nfw,
                       const float* ir) {
  long id = (long)blockIdx.x*256 + threadIdx.x;
  if (id < R_WIN) {
    double w = 0.5 - 0.5*cos(2.0*M_PI*(double)id/1024.0);
    W[oWIN+id] = (float)w; return;
  } id -= R_WIN;
  if (id < R_TW) {
    double a = -2.0*M_PI*(double)id/1024.0;
    W[oTW+2*id] = (float)cos(a); W[oTW+2*id+1] = (float)sin(a); return;
  } id -= R_TW;
  if (id < R_AW) {
    double fr = (double)id*(8000.0/512.0); double fsq = fr*fr;
    double num = 12194.217*12194.217*fsq*fsq;
    double den = (fsq+20.6*20.6)*(fsq+107.7*107.7)*(fsq+737.9*737.9)*sqrt(fsq+12194.217*12194.217) + 1e-8;
    W[oAW+id] = (float)(num/den); return;
  } id -= R_AW;
  if (id < R_MELFB) {
    int k = (int)(id/80), m = (int)(id%80);
    double fk = (double)k*(8000.0/512.0);
    double f0p = mel_fpt(m), f1p = mel_fpt(m+1), f2p = mel_fpt(m+2);
    double lower = (fk - f0p)/(f1p - f0p);
    double upper = (f2p - fk)/(f2p - f1p);
    double v = fmax(0.0, fmin(lower, upper));
    W[oMELFB+id] = (float)v; return;
  } id -= R_MELFB;
  if (id < R_WSQI) {
    int t = (int)id;
    int n1 = t/256; if (n1 > 625) n1 = 625;
    int n0t = t - 1023 + 255; int n0 = (n0t > 0) ? n0t/256 : 0;
    double s = 0.0;
    for (int n = n0; n <= n1; ++n) {
      int o = t - n*256;
      double wv = 0.5 - 0.5*cos(2.0*M_PI*(double)o/1024.0);
      s += wv*wv;
    }
    float sf = (float)s;
    W[oWSQI+t] = (sf > 1e-11f) ? (1.0f/sf) : 1.0f; return;
  } id -= R_WSQI;
  if (id < R_WIHT) { long k = id/768, g = id%768; W[oWIHT+id] = wih[g*80+k];  return; } id -= R_WIHT;
  if (id < R_W0T)  { long d = id/512, j = id%512; W[oW0T+id] = w0[j*21+d];   return; } id -= R_W0T;
  if (id < R_W1T)  { long k = id/512, j = id%512; W[oW1T+id] = w1[j*512+k];  return; } id -= R_W1T;
  if (id < R_W2T)  { long k = id/512, j = id%512; W[oW2T+id] = w2[j*512+k];  return; } id -= R_W2T;
  if (id < R_VTT)  { long k = id/65,  m = id%65;  W[oVTT+id] = vtw[m*512+k]; return; } id -= R_VTT;
  if (id < R_NFT)  { long k = id/65,  m = id%65;  W[oNFT+id] = nfw[m*512+k]; return; } id -= R_NFT;
  if (id < R_IR) {
    size_t base = oCONVA + 2*((size_t)8*NCONV + id);
    W[base] = (id < 8000) ? ir[id] : 0.0f; W[base+1] = 0.0f; return;
  }
}

__global__ void k_zacc(float* W) {
  size_t id = (size_t)blockIdx.x*256 + threadIdx.x;
  if (id < (size_t)BB*ACCLEN) W[oACC+id] = 0.0f;
}

// ---------------- f0 via direct linear autocorrelation ----------------
__global__ __launch_bounds__(320) void k_f0(const float* audio, float* W) {
  int blk = blockIdx.x; int b = blk/FRM, f = blk%FRM; int tid = threadIdx.x;
  __shared__ float fr[1024];
  __shared__ float val[304];
  __shared__ float psum[320];
  const float* arow = audio + (size_t)b*TLEN;
  for (int i = tid; i < 1024; i += 320) fr[i] = arow[mirror_idx(f*256 + i - 512)];
  __syncthreads();
  float p = 0.f;
  for (int i = tid; i < 1024; i += 320) p += fr[i]*fr[i];
  psum[tid] = p;
  if (tid < 304) {
    int lag = 16 + tid; float s = 0.f;
    for (int t0 = 0; t0 < 1024; ++t0) if (t0 + lag < 1024) s += fr[t0]*fr[t0+lag];
    val[tid] = s;
  }
  __syncthreads();
  if (tid == 0) {
    float ac0 = 0.f;
    for (int i = 0; i < 320; ++i) ac0 += psum[i];
    float inv = 1.0f/(ac0 + 1e-8f);
    float best = -1e30f; int bi = 0;
    for (int i = 0; i < 304; ++i) { float v = val[i]*inv; if (v > best) { best = v; bi = i; } }
    float f0v = (best < 0.3f) ? 0.0f : (SRF/(float)(bi + 16));
    W[oF0 + blk] = f0v;
  }
}

// ---------------- STFT of audio + loud + mel ----------------
__global__ __launch_bounds__(256) void k_stft_mel(const float* audio, float* W) {
  int blk = blockIdx.x; int b = blk/FRM, f = blk%FRM; int tid = threadIdx.x;
  __shared__ float re[1024], im[1024], spec[513];
  __shared__ float redbuf[4];
  const float* arow = audio + (size_t)b*TLEN;
  const float* tw = W + oTW;
  for (int i = tid; i < 1024; i += 256) {
    float v = arow[mirror_idx(f*256 + i - 512)] * W[oWIN + i];
    int pos = __brev((unsigned)i) >> 22;
    re[pos] = v; im[pos] = 0.f;
  }
  __syncthreads();
  fft_lds<10,1>(re, im, tw, tid, 256, false);
  for (int k = tid; k < 513; k += 256) spec[k] = re[k]*re[k] + im[k]*im[k];
  __syncthreads();
  float part = 0.f;
  for (int k = tid; k < 513; k += 256) part += (spec[k] + 1e-8f) * W[oAW + k];
  for (int off = 32; off; off >>= 1) part += __shfl_down(part, off, 64);
  if ((tid & 63) == 0) redbuf[tid >> 6] = part;
  __syncthreads();
  if (tid == 0) {
    float s = redbuf[0]+redbuf[1]+redbuf[2]+redbuf[3];
    W[oLOUD + blk] = 10.0f * log10f(s / 513.0f);
  }
  for (int m = tid; m < 80; m += 256) {
    float s = 0.f;
    for (int k = 0; k < 513; ++k) s += spec[k]*W[oMELFB + (size_t)k*80 + m];
    W[oMEL + (size_t)blk*80 + m] = logf(s + 1e-5f);
  }
}

// ---------------- mel normalization over time ----------------
__global__ void k_melnorm(float* W) {
  int id = blockIdx.x*256 + threadIdx.x;
  if (id >= BB*80) return;
  int b = id/80, m = id%80;
  double s = 0.0, ss = 0.0;
  for (int f = 0; f < FRM; ++f) {
    double v = W[oMEL + ((size_t)b*FRM + f)*80 + m];
    s += v; ss += v*v;
  }
  double mean = s/FRM;
  double var = ss/FRM - mean*mean;
  float mu = (float)mean;
  float rstd = (float)(1.0/sqrt(var + 1e-5));
  for (int f = 0; f < FRM; ++f) {
    size_t idx = oMEL + ((size_t)b*FRM + f)*80 + m;
    W[idx] = (W[idx] - mu)*rstd;
  }
}

// ---------------- GRU input precompute ----------------
__global__ void k_xp(float* W, const float* bih) {
  size_t id = (size_t)blockIdx.x*256 + threadIdx.x;
  if (id >= (size_t)NFRM*768) return;
  int g = (int)(id % 768);
  size_t q = id / 768;
  const float* mrow = W + oMEL + q*80;
  float acc = bih[g];
  for (int k = 0; k < 80; ++k) acc = fmaf(mrow[k], W[oWIHT + (size_t)k*768 + g], acc);
  W[oXP + q*768 + g] = acc;
}

// ---------------- persistent MFMA GRU: 1 block, 512 threads, all 8 batches ----------------
// Weights bf16: 32 reg fragments/lane (tiles 6w..6w+3) + LDS tiles (6w+4, 6w+5).
// A = h (16x256, rows 8..15 zero), B = whh^T slice, C rows = batches.
// Layouts (learn_hip m89/m91-verified family):
//   A: lane l elem j -> A[l&15][(l>>4)*8+j]; B: lane l elem j -> B[(l>>4)*8+j][l&15]
//   C: acc[j] -> C[(l>>4)*4+j][l&15]
__global__ __launch_bounds__(512, 2) void k_gru_mfma(float* W, const float* whh, const float* bhh) {
  __shared__ unsigned short sB[65536];   // 128 KB  [lcol][k^((lcol&7)<<3)]
  __shared__ unsigned short sA[4096];    // 8 KB    [row][k^((row&7)<<3)]
  __shared__ unsigned short sGH[6144];   // 12 KB   [b][col]
  int tid = threadIdx.x;
  int w = tid >> 6, l = tid & 63;
  const float* XP = W + oXP;
  float* HS = W + oHS;

  // fill LDS B: lcol in [0,256): wave (lcol>>5) cols [96w+64, 96w+96)
  for (int idx = tid; idx < 65536; idx += 512) {
    int lcol = idx >> 8, k = idx & 255;
    int gcol = 96*(lcol >> 5) + 64 + (lcol & 31);
    sB[lcol*256 + (k ^ ((lcol & 7) << 3))] = f2bf(whh[(size_t)gcol*256 + k]);
  }
  for (int idx = tid; idx < 4096; idx += 512) sA[idx] = 0;

  // register B fragments: tiles 6w+0..3
  int cl = l & 15, khalf = (l >> 4) * 8;
  bf16x8 bw[32];
  #pragma unroll
  for (int t2 = 0; t2 < 4; ++t2) {
    int col = (6*w + t2)*16 + cl;
    #pragma unroll
    for (int kk = 0; kk < 8; ++kk) {
      const float* src = whh + (size_t)col*256 + kk*32 + khalf;
      short8 tmp;
      #pragma unroll
      for (int j = 0; j < 8; ++j) tmp[j] = (short)f2bf(src[j]);
      bw[t2*8 + kk] = __builtin_bit_cast(bf16x8, tmp);
    }
  }

  int g = tid & 255, bbase = tid >> 8;   // bbase in {0,1}; tasks b = bbase+2j
  float bh_r = bhh[g], bh_z = bhh[256 + g], bh_n = bhh[512 + g];
  float hprev[4] = {0.f, 0.f, 0.f, 0.f};
  int aXor = (cl & 7) << 3;
  int lcol0 = w*32 + cl, lcol1 = w*32 + 16 + cl;

  __syncthreads();

#define LDA(kk) (*(const bf16x8*)&sA[(cl)*256 + (((kk)*32 + khalf) ^ aXor)])
#define LDB(lc, kk) (*(const bf16x8*)&sB[(lc)*256 + (((kk)*32 + khalf) ^ aXor)])
#define STEPK(A_, kk) \
    c0 = MFMA_BF16(A_, bw[0*8+(kk)], c0, 0, 0, 0); \
    c1 = MFMA_BF16(A_, bw[1*8+(kk)], c1, 0, 0, 0); \
    c2 = MFMA_BF16(A_, bw[2*8+(kk)], c2, 0, 0, 0); \
    c3 = MFMA_BF16(A_, bw[3*8+(kk)], c3, 0, 0, 0); \
    c4 = MFMA_BF16(A_, LDB(lcol0, kk), c4, 0, 0, 0); \
    c5 = MFMA_BF16(A_, LDB(lcol1, kk), c5, 0, 0, 0);

  for (int t = 0; t < FRM; ++t) {
    // xp loads (issued early, consumed in P3)
    float xr[4], xz[4], xn[4];
    #pragma unroll
    for (int j = 0; j < 4; ++j) {
      const float* xpp = XP + ((size_t)(bbase + 2*j)*FRM + t)*768 + g;
      xr[j] = xpp[0]; xz[j] = xpp[256]; xn[j] = xpp[512];
    }
    // P2: MFMA
    f32x4 c0 = {0,0,0,0}, c1 = {0,0,0,0}, c2 = {0,0,0,0};
    f32x4 c3 = {0,0,0,0}, c4 = {0,0,0,0}, c5 = {0,0,0,0};
    bf16x8 a0 = LDA(0), a1 = LDA(1), a2 = LDA(2), a3 = LDA(3);
    STEPK(a0, 0) STEPK(a1, 1) STEPK(a2, 2) STEPK(a3, 3)
    a0 = LDA(4); a1 = LDA(5); a2 = LDA(6); a3 = LDA(7);
    STEPK(a0, 4) STEPK(a1, 5) STEPK(a2, 6) STEPK(a3, 7)
    // write gate pre-activations to sGH (rows 0..7 only)
    int rowg = l >> 4;
    if (rowg < 2) {
      #pragma unroll
      for (int j = 0; j < 4; ++j) {
        int row = rowg*4 + j;
        sGH[row*768 + (6*w + 0)*16 + cl] = f2bf(c0[j]);
        sGH[row*768 + (6*w + 1)*16 + cl] = f2bf(c1[j]);
        sGH[row*768 + (6*w + 2)*16 + cl] = f2bf(c2[j]);
        sGH[row*768 + (6*w + 3)*16 + cl] = f2bf(c3[j]);
        sGH[row*768 + (6*w + 4)*16 + cl] = f2bf(c4[j]);
        sGH[row*768 + (6*w + 5)*16 + cl] = f2bf(c5[j]);
      }
    }
    __syncthreads();
    // P3: gate math, h update (f32), publish h as bf16 A-staging
    #pragma unroll
    for (int j = 0; j < 4; ++j) {
      int bb = bbase + 2*j;
      float ghr = bf2f(sGH[bb*768 + g]);
      float ghz = bf2f(sGH[bb*768 + 256 + g]);
      float ghn = bf2f(sGH[bb*768 + 512 + g]);
      float r = 1.0f/(1.0f + __expf(-(xr[j] + ghr + bh_r)));
      float z = 1.0f/(1.0f + __expf(-(xz[j] + ghz + bh_z)));
      float nn = tanhf(xn[j] + r*(ghn + bh_n));
      float h = (1.0f - z)*nn + z*hprev[j];
      hprev[j] = h;
      HS[((size_t)bb*FRM + t)*256 + g] = h;
      sA[bb*256 + (g ^ ((bb & 7) << 3))] = f2bf(h);
    }
    __syncthreads();
  }
#undef LDA
#undef LDB
#undef STEPK
}

// ---------------- projection ----------------
__global__ void k_proj(float* W, const float* projw, const float* projb) {
  size_t id = (size_t)blockIdx.x*256 + threadIdx.x;
  if (id >= (size_t)NFRM*16) return;
  int zi = (int)(id % 16);
  size_t q = id / 16;
  const float* hrow = W + oHS + q*256;
  float acc = projb[zi];
  for (int k = 0; k < 256; ++k) acc = fmaf(hrow[k], projw[zi*256 + k], acc);
  W[oZ + q*16 + zi] = acc;
}

// ---------------- MLP + heads ----------------
__device__ inline void ln_lrelu(float acc[8], float gj, float ej, float out[8][512],
                                float wred[8][8][2], float stat[8][2],
                                int tid, int lane, int wv, int j) {
  #pragma unroll
  for (int i = 0; i < 8; ++i) {
    float s = acc[i], ss = acc[i]*acc[i];
    for (int off = 32; off; off >>= 1) { s += __shfl_down(s, off, 64); ss += __shfl_down(ss, off, 64); }
    if (lane == 0) { wred[i][wv][0] = s; wred[i][wv][1] = ss; }
  }
  __syncthreads();
  if (tid < 8) {
    float s = 0.f, ss = 0.f;
    #pragma unroll
    for (int w = 0; w < 8; ++w) { s += wred[tid][w][0]; ss += wred[tid][w][1]; }
    float mean = s/512.0f;
    float var = ss/512.0f - mean*mean;
    stat[tid][0] = mean;
    stat[tid][1] = 1.0f/sqrtf(var + 1e-5f);
  }
  __syncthreads();
  #pragma unroll
  for (int i = 0; i < 8; ++i) {
    float v = (acc[i] - stat[i][0])*stat[i][1]*gj + ej;
    out[i][j] = (v >= 0.f) ? v : 0.1f*v;
  }
}

__global__ __launch_bounds__(512) void k_mlp(float* W, const float* gender, const float* age,
    const float* b0, const float* g0, const float* e0,
    const float* b1, const float* g1, const float* e1,
    const float* b2, const float* g2, const float* e2,
    const float* oqw, const float* oqb, const float* vtb, const float* nfb) {
  __shared__ float in0[8][21];
  __shared__ float actA[8][512];
  __shared__ float actB[8][512];
  __shared__ float wred[8][8][2];
  __shared__ float stat[8][2];
  int tid = threadIdx.x; int q0 = blockIdx.x*8;
  if (tid < 168) {
    int i = tid/21, d = tid%21; int q = q0 + i; int b = q/FRM;
    float v;
    if (d < 16) v = W[oZ + (size_t)q*16 + d];
    else if (d == 16) v = (logf(W[oF0 + q] + 1e-5f) - 4.0f)*0.25f;
    else if (d == 17) v = W[oLOUD + q]/100.0f + 1.0f;
    else if (d == 18) v = gender[b*2];
    else if (d == 19) v = gender[b*2 + 1];
    else v = age[b];
    in0[i][d] = v;
  }
  __syncthreads();
  int j = tid, lane = tid & 63, wv = tid >> 6;
  float acc[8];
  #pragma unroll
  for (int i = 0; i < 8; ++i) acc[i] = b0[j];
  for (int d = 0; d < 21; ++d) {
    float w = W[oW0T + (size_t)d*512 + j];
    #pragma unroll
    for (int i = 0; i < 8; ++i) acc[i] = fmaf(in0[i][d], w, acc[i]);
  }
  ln_lrelu(acc, g0[j], e0[j], actA, wred, stat, tid, lane, wv, j);
  __syncthreads();
  #pragma unroll
  for (int i = 0; i < 8; ++i) acc[i] = b1[j];
  for (int k = 0; k < 512; ++k) {
    float w = W[oW1T + (size_t)k*512 + j];
    #pragma unroll
    for (int i = 0; i < 8; ++i) acc[i] = fmaf(actA[i][k], w, acc[i]);
  }
  ln_lrelu(acc, g1[j], e1[j], actB, wred, stat, tid, lane, wv, j);
  __syncthreads();
  #pragma unroll
  for (int i = 0; i < 8; ++i) acc[i] = b2[j];
  for (int k = 0; k < 512; ++k) {
    float w = W[oW2T + (size_t)k*512 + j];
    #pragma unroll
    for (int i = 0; i < 8; ++i) acc[i] = fmaf(actB[i][k], w, acc[i]);
  }
  ln_lrelu(acc, g2[j], e2[j], actA, wred, stat, tid, lane, wv, j);
  __syncthreads();
  for (int x = tid; x < 520; x += 512) {
    int i = x/65, m = x%65;
    float a = vtb[m], a2 = nfb[m];
    for (int k = 0; k < 512; ++k) {
      float h = actA[i][k];
      a  = fmaf(h, W[oVTT + (size_t)k*65 + m], a);
      a2 = fmaf(h, W[oNFT + (size_t)k*65 + m], a2);
    }
    W[oVT + (size_t)(q0+i)*65 + m] = sigm(a);
    W[oNF + (size_t)(q0+i)*65 + m] = sigm(a2);
  }
  if (tid < 8) {
    float a = oqb[0];
    for (int k = 0; k < 512; ++k) a = fmaf(actA[tid][k], oqw[k], a);
    W[oOQ + q0 + tid] = sigm(a);
  }
}

// ---------------- noise: JAX threefry partitionable, key (0,42), bits = o0^o1 ----------------
__global__ void k_noise(float* W) {
  int p = blockIdx.x*256 + threadIdx.x;
  if (p >= BB*TLEN) return;
  unsigned o0, o1;
  threefry2x32(0u, 42u, 0u, (unsigned)p, o0, o1);
  W[oNOISE + p] = normal_from_bits(o0 ^ o1);
}

// ---------------- glottal ----------------
__global__ __launch_bounds__(256) void k_glottal(float* W) {
  int b = blockIdx.x; int tid = threadIdx.x;
  __shared__ float wsums[4];
  __shared__ float gbuf[256];
  __shared__ double carry_sh;
  __shared__ float gprev_sh, ctot_sh;
  const float* f0r = W + oF0 + (size_t)b*FRM;
  const float* oqr = W + oOQ + (size_t)b*FRM;
  float* grow = W + oGLOT + (size_t)b*TLEN;
  if (tid == 0) { carry_sh = 0.0; gprev_sh = 0.f; }
  __syncthreads();
  int lane = tid & 63, wv = tid >> 6;
  for (int c = 0; c < TLEN/256; ++c) {
    int i = c*256 + tid;
    float v = interpF(f0r, i) / SRF;
    float s = v;
    #pragma unroll
    for (int off = 1; off < 64; off <<= 1) {
      float o = __shfl_up(s, off, 64);
      if (lane >= off) s += o;
    }
    if (lane == 63) wsums[wv] = s;
    __syncthreads();
    float wpre = 0.f;
    for (int wwi = 0; wwi < wv; ++wwi) wpre += wsums[wwi];
    float ph = (float)(carry_sh + (double)(wpre + s));
    float p = ph - floorf(ph);
    float oqu = interpF(oqr, i);
    float oqc = fminf(fmaxf(oqu, 0.1f), 0.9f);
    float pulse = 0.5f*(1.0f - cosf(3.14159265358979f * p / (oqc + 1e-8f)));
    float gs = 1.0f/(1.0f + expf(-(oqc - p)*100.0f));
    float g = pulse*gs;
    gbuf[tid] = g;
    if (tid == 255) ctot_sh = wpre + s;
    __syncthreads();
    float gl = (tid == 0) ? gprev_sh : gbuf[tid-1];
    grow[i] = (i == 0) ? 0.f : (g - gl);
    __syncthreads();
    if (tid == 0) { carry_sh += (double)ctot_sh; gprev_sh = gbuf[255]; }
    __syncthreads();
  }
}

// ---------------- fused STFT->filter->ISTFT OLA ----------------
__global__ __launch_bounds__(256) void k_filtsynth(float* W) {
  int blk = blockIdx.x; int b = blk/FRM, f = blk%FRM; int tid = threadIdx.x;
  __shared__ float reG[1024], imG[1024], reN[1024], imN[1024];
  __shared__ float fvt[65], fnf[65];
  const float* grow = W + oGLOT + (size_t)b*TLEN;
  const float* nrow = W + oNOISE + (size_t)b*TLEN;
  const float* tw = W + oTW;
  for (int i = tid; i < 1024; i += 256) {
    int si = mirror_idx(f*256 + i - 512);
    float wv = W[oWIN + i];
    int pos = __brev((unsigned)i) >> 22;
    reG[pos] = grow[si]*wv; imG[pos] = 0.f;
    reN[pos] = nrow[si]*wv; imN[pos] = 0.f;
  }
  if (tid < 65) {
    fvt[tid] = W[oVT + ((size_t)b*FRM + f)*65 + tid];
    fnf[tid] = W[oNF + ((size_t)b*FRM + f)*65 + tid];
  }
  __syncthreads();
  fft_lds<10,1>(reG, imG, tw, tid, 256, false);
  fft_lds<10,1>(reN, imN, tw, tid, 256, false);
  for (int k = tid; k < 1024; k += 256) {
    int kp = min(k, 1024 - k);
    float fv = interp65(fvt, kp);
    float fn = interp65(fnf, kp);
    reG[k] = reG[k]*fv + reN[k]*fn;
    imG[k] = imG[k]*fv + imN[k]*fn;
  }
  __syncthreads();
  for (int i = tid; i < 1024; i += 256) {
    int jj = __brev((unsigned)i) >> 22;
    if (jj > i) {
      float tr = reG[i]; reG[i] = reG[jj]; reG[jj] = tr;
      float ti = imG[i]; imG[i] = imG[jj]; imG[jj] = ti;
    }
  }
  __syncthreads();
  fft_lds<10,1>(reG, imG, tw, tid, 256, true);
  float* arow = W + oACC + (size_t)b*ACCLEN + (size_t)f*256;
  for (int i = tid; i < 1024; i += 256) {
    float xv = reG[i]*(1.0f/1024.0f)*W[oWIN + i];
    atomicAdd(arow + i, xv);
  }
}

// ---------------- dry ----------------
__global__ void k_dry(float* W, float* dout) {
  size_t id = (size_t)blockIdx.x*256 + threadIdx.x;
  if (id >= (size_t)BB*NCONV) return;
  int b = (int)(id / NCONV);
  int n = (int)(id % NCONV);
  float dv = 0.f;
  if (n < TLEN) {
    float val = W[oACC + (size_t)b*ACCLEN + 512 + n] * W[oWSQI + 512 + n];
    const float* lrow = W + oLOUD + (size_t)b*FRM;
    float pos = ((float)n + 0.5f) * (626.0f/160000.0f) - 0.5f;
    pos = fminf(fmaxf(pos, 0.0f), 625.0f);
    int lo = (int)floorf(pos);
    int hi = min(lo + 1, 625);
    float w = pos - (float)lo;
    float a0 = exp10f(lrow[lo]*0.05f);
    float a1 = exp10f(lrow[hi]*0.05f);
    float ampu = a0*(1.0f - w) + a1*w;
    dv = val*ampu;
    dout[(size_t)BB*TLEN + (size_t)b*TLEN + n] = dv;
  }
  W[oCONVA + 2*id] = dv;
  W[oCONVA + 2*id + 1] = 0.f;
}

// ---------------- four-step FFT (N = 512*512) ----------------
__global__ __launch_bounds__(256) void k_conv_f1(const float* in, float* out, const float* tw) {
  int blk = blockIdx.x; int t = blk >> 9; int bcol = blk & 511; int tid = threadIdx.x;
  __shared__ float re[512], im[512];
  const float* src = in + (size_t)t*NCONV*2;
  for (int a = tid; a < 512; a += 256) {
    int pos = __brev((unsigned)a) >> 23;
    size_t idx = 2*((size_t)a*512 + bcol);
    re[pos] = src[idx]; im[pos] = src[idx+1];
  }
  __syncthreads();
  fft_lds<9,2>(re, im, tw, tid, 256, false);
  float* dst = out + (size_t)t*NCONV*2 + (size_t)bcol*512*2;
  for (int k1 = tid; k1 < 512; k1 += 256) {
    long bk = (long)bcol*k1;
    float ang = -6.283185307179586f * ((float)bk * (1.0f/262144.0f));
    float sv, cv; sincosf(ang, &sv, &cv);
    float r = re[k1], iv = im[k1];
    dst[2*k1]   = r*cv - iv*sv;
    dst[2*k1+1] = r*sv + iv*cv;
  }
}

__global__ __launch_bounds__(256) void k_conv_f2(const float* in, float* out, const float* tw) {
  int blk = blockIdx.x; int t = blk >> 9; int k1 = blk & 511; int tid = threadIdx.x;
  __shared__ float re[512], im[512];
  const float* src = in + (size_t)t*NCONV*2;
  for (int bb2 = tid; bb2 < 512; bb2 += 256) {
    int pos = __brev((unsigned)bb2) >> 23;
    size_t idx = 2*((size_t)bb2*512 + k1);
    re[pos] = src[idx]; im[pos] = src[idx+1];
  }
  __syncthreads();
  fft_lds<9,2>(re, im, tw, tid, 256, false);
  float* dst = out + (size_t)t*NCONV*2;
  for (int k2 = tid; k2 < 512; k2 += 256) {
    size_t idx = 2*((size_t)k1 + 512*(size_t)k2);
    dst[idx] = re[k2]; dst[idx+1] = im[k2];
  }
}

__global__ void k_mul(float* W) {
  size_t id = (size_t)blockIdx.x*256 + threadIdx.x;
  if (id >= (size_t)BB*NCONV) return;
  size_t k = id % NCONV;
  float* A = W + oCONVA;
  float ar = A[2*id], ai = A[2*id+1];
  size_t ic = 2*((size_t)8*NCONV + k);
  float cr = A[ic], ci = A[ic+1];
  float pr = ar*cr - ai*ci;
  float pi = ar*ci + ai*cr;
  A[2*id] = pr;
  A[2*id+1] = -pi;
}

__global__ void k_wet(const float* W, float* dout) {
  size_t id = (size_t)blockIdx.x*256 + threadIdx.x;
  if (id >= (size_t)BB*TLEN) return;
  size_t b = id / TLEN, n = id % TLEN;
  dout[id] = W[oCONVA + 2*(b*NCONV + n)] * (1.0f/262144.0f);
}

// ---------------- launch ----------------
extern "C" void kernel_launch(void* const* d_in, const int* in_sizes, int n_in,
                              void* d_out, int out_size, void* d_ws, size_t ws_size,
                              hipStream_t stream) {
  (void)in_sizes; (void)n_in; (void)out_size; (void)ws_size;
  const float* audio  = (const float*)d_in[0];
  const float* gender = (const float*)d_in[1];
  const float* age    = (const float*)d_in[2];
  const float* wih    = (const float*)d_in[3];
  const float* whh    = (const float*)d_in[4];
  const float* bih    = (const float*)d_in[5];
  const float* bhh    = (const float*)d_in[6];
  const float* projw  = (const float*)d_in[7];
  const float* projb  = (const float*)d_in[8];
  const float* w0     = (const float*)d_in[9];
  const float* b0     = (const float*)d_in[10];
  const float* g0     = (const float*)d_in[11];
  const float* e0     = (const float*)d_in[12];
  const float* w1     = (const float*)d_in[13];
  const float* b1     = (const float*)d_in[14];
  const float* g1     = (const float*)d_in[15];
  const float* e1     = (const float*)d_in[16];
  const float* w2     = (const float*)d_in[17];
  const float* b2     = (const float*)d_in[18];
  const float* g2     = (const float*)d_in[19];
  const float* e2     = (const float*)d_in[20];
  const float* oqw    = (const float*)d_in[21];
  const float* oqb    = (const float*)d_in[22];
  const float* vtw    = (const float*)d_in[23];
  const float* vtb    = (const float*)d_in[24];
  const float* nfw    = (const float*)d_in[25];
  const float* nfb    = (const float*)d_in[26];
  const float* ir     = (const float*)d_in[27];
  float* W = (float*)d_ws;
  float* dout = (float*)d_out;

  k_init<<<(int)((INIT_TOTAL + 255)/256), 256, 0, stream>>>(W, wih, w0, w1, w2, vtw, nfw, ir);
  k_f0<<<NFRM, 320, 0, stream>>>(audio, W);
  k_stft_mel<<<NFRM, 256, 0, stream>>>(audio, W);
  k_melnorm<<<3, 256, 0, stream>>>(W);
  k_xp<<<(int)(((size_t)NFRM*768 + 255)/256), 256, 0, stream>>>(W, bih);
  k_gru_mfma<<<1, 512, 0, stream>>>(W, whh, bhh);
  k_proj<<<(int)(((size_t)NFRM*16 + 255)/256), 256, 0, stream>>>(W, projw, projb);
  k_mlp<<<NFRM/8, 512, 0, stream>>>(W, gender, age, b0, g0, e0, b1, g1, e1, b2, g2, e2, oqw, oqb, vtb, nfb);
  k_zacc<<<(int)(((size_t)BB*ACCLEN + 255)/256), 256, 0, stream>>>(W);
  k_noise<<<(BB*TLEN + 255)/256, 256, 0, stream>>>(W);
  k_glottal<<<BB, 256, 0, stream>>>(W);
  k_filtsynth<<<NFRM, 256, 0, stream>>>(W);
  k_dry<<<(int)(((size_t)BB*NCONV + 255)/256), 256, 0, stream>>>(W, dout);
  k_conv_f1<<<9*512, 256, 0, stream>>>(W + oCONVA, W + oCONVB, W + oTW);
  k_conv_f2<<<9*512, 256, 0, stream>>>(W + oCONVB, W + oCONVA, W + oTW);
  k_mul<<<(int)(((size_t)BB*NCONV + 255)/256), 256, 0, stream>>>(W);
  k_conv_f1<<<8*512, 256, 0, stream>>>(W + oCONVA, W + oCONVB, W + oTW);
  k_conv_f2<<<8*512, 256, 0, stream>>>(W + oCONVB, W + oCONVA, W + oTW);
  k_wet<<<(int)(((size_t)BB*TLEN + 255)/256), 256, 0, stream>>>(W, dout);
}

// Round 6
// 2690.665 us; speedup vs baseline: 2.4332x; 1.2531x over previous
//
#include <hip/hip_runtime.h>
#include <math.h>

#define SRF 16000.0f
#define HOP 256
#define FRM 626
#define BB 8
#define TLEN 160000
#define NFRM (BB*FRM)
#define NCONV 262144
#define ACCLEN 161024

// ---------------- workspace layout (float offsets) ----------------
constexpr size_t oWIN   = 0;                       // 1024
constexpr size_t oTW    = oWIN + 1024;             // 1024 (512 complex, angle -2pi r/1024)
constexpr size_t oDIAG  = oTW + 1024;              // 16 (unused)
constexpr size_t oTWF   = oDIAG + 16;              // 1024 (512 complex, angle -2pi r/262144)
constexpr size_t oTWC   = oTWF + 1024;             // 1024 (512 complex, angle -2pi r/512)
constexpr size_t oAW    = oTWC + 1024;             // 513
constexpr size_t oMELFB = oAW + 513;               // 41040
constexpr size_t oWSQI  = oMELFB + 513*80;         // 161024
constexpr size_t oWIHT  = oWSQI + ACCLEN;          // 61440
constexpr size_t oW0T   = oWIHT + 80*768;          // 10752
constexpr size_t oW1T   = oW0T + 21*512;           // 262144
constexpr size_t oW2T   = oW1T + 512*512;          // 262144
constexpr size_t oVTT   = oW2T + 512*512;          // 33280
constexpr size_t oNFT   = oVTT + 512*65;           // 33280
constexpr size_t oF0    = oNFT + 512*65;           // 5008
constexpr size_t oLOUD  = oF0 + NFRM;              // 5008
constexpr size_t oOQ    = oLOUD + NFRM;            // 5008
constexpr size_t oVT    = oOQ + NFRM;              // 325520
constexpr size_t oNF    = oVT + (size_t)NFRM*65;   // 325520
constexpr size_t oGLOT  = oNF + (size_t)NFRM*65;   // 1280000
constexpr size_t oNOISE = oGLOT + (size_t)BB*TLEN; // 1280000
constexpr size_t oACC   = oNOISE + (size_t)BB*TLEN;// 1288192
constexpr size_t oCONVA = oACC + (size_t)BB*ACCLEN;// 4718592
constexpr size_t oEND   = oCONVA + (size_t)9*NCONV*2;
// overlays (lifetime-checked):
constexpr size_t oCONVB = oWSQI;                      // conv scratch; WSQI..ACC dead at conv time
constexpr size_t oXP    = oGLOT;                      // GRU input; dead before noise/glottal/zacc
constexpr size_t oMEL = oCONVA;                       // dead before k_dry packs CONVA
constexpr size_t oHS  = oMEL + (size_t)NFRM*80;
constexpr size_t oZ   = oHS + (size_t)NFRM*256;       // ends well below CONVA+8*NCONV*2 (ir slot)

// init task counts
constexpr long R_WIN=1024, R_TW=512, R_TWF=512, R_TWC=512, R_AW=513, R_MELFB=41040,
  R_WSQI=161024, R_WIHT=61440, R_W0T=10752, R_W1T=262144, R_W2T=262144,
  R_VTT=33280, R_NFT=33280, R_IR=NCONV;
constexpr long INIT_TOTAL = R_WIN+R_TW+R_TWF+R_TWC+R_AW+R_MELFB+R_WSQI+R_WIHT+R_W0T+
  R_W1T+R_W2T+R_VTT+R_NFT+R_IR;

typedef float f32x4 __attribute__((ext_vector_type(4)));
typedef __bf16 bf16x8 __attribute__((ext_vector_type(8)));
typedef short short8 __attribute__((ext_vector_type(8)));
#define MFMA_BF16 __builtin_amdgcn_mfma_f32_16x16x32_bf16

// ---------------- helpers ----------------
__device__ inline int mirror_idx(int j) {
  if (j < 0) j = -j;
  if (j >= TLEN) j = 2*TLEN - 2 - j;
  return j;
}
__device__ inline float sigm(float x) { return 1.0f/(1.0f + expf(-x)); }
__device__ inline unsigned short f2bf(float x) {
  unsigned u = __float_as_uint(x);
  return (unsigned short)((u + 0x7FFFu + ((u >> 16) & 1u)) >> 16);
}
__device__ inline float tanh_fast(float x) {
  return 1.0f - 2.0f/(__expf(2.0f*x) + 1.0f);
}

__device__ inline float interpF(const float* v, int i) {
  float pos = ((float)i + 0.5f) * (626.0f/160000.0f) - 0.5f;
  pos = fminf(fmaxf(pos, 0.0f), 625.0f);
  int lo = (int)floorf(pos);
  int hi = min(lo + 1, 625);
  float w = pos - (float)lo;
  return v[lo]*(1.0f - w) + v[hi]*w;
}
__device__ inline float interp65(const float* v, int k) {
  float pos = ((float)k + 0.5f) * (65.0f/513.0f) - 0.5f;
  pos = fminf(fmaxf(pos, 0.0f), 64.0f);
  int lo = (int)floorf(pos);
  int hi = min(lo + 1, 64);
  float w = pos - (float)lo;
  return v[lo]*(1.0f - w) + v[hi]*w;
}

// radix-2 DIT FFT in LDS on interleaved complex; input at bit-reversed positions.
template<int LOGN, int TS>
__device__ inline void fft2(float2* c, const float2* tw, int tid, int nthr, bool inv) {
  constexpr int N = 1 << LOGN;
  for (int s = 1; s <= LOGN; ++s) {
    const int half = 1 << (s-1);
    const int tstep = (N >> s) * TS;
    for (int bf = tid; bf < (N>>1); bf += nthr) {
      int jj = bf & (half-1);
      int i0 = ((bf >> (s-1)) << s) + jj;
      int i1 = i0 + half;
      float2 wv = tw[jj*tstep];
      float wi = inv ? -wv.y : wv.y;
      float2 u = c[i0], v = c[i1];
      float tr  = v.x*wv.x - v.y*wi;
      float tci = v.x*wi  + v.y*wv.x;
      c[i0] = make_float2(u.x + tr, u.y + tci);
      c[i1] = make_float2(u.x - tr, u.y - tci);
    }
    __syncthreads();
  }
}

// threefry2x32, canonical 20-round schedule
__device__ inline void threefry2x32(unsigned k0, unsigned k1, unsigned x0, unsigned x1,
                                    unsigned& o0, unsigned& o1) {
  unsigned ks2 = k0 ^ k1 ^ 0x1BD11BDAu;
  x0 += k0; x1 += k1;
#define TF_R(r) { x0 += x1; x1 = (x1<<(r)) | (x1>>(32-(r))); x1 ^= x0; }
  TF_R(13) TF_R(15) TF_R(26) TF_R(6)
  x0 += k1; x1 += ks2 + 1u;
  TF_R(17) TF_R(29) TF_R(16) TF_R(24)
  x0 += ks2; x1 += k0 + 2u;
  TF_R(13) TF_R(15) TF_R(26) TF_R(6)
  x0 += k0; x1 += k1 + 3u;
  TF_R(17) TF_R(29) TF_R(16) TF_R(24)
  x0 += k1; x1 += ks2 + 4u;
  TF_R(13) TF_R(15) TF_R(26) TF_R(6)
  x0 += ks2; x1 += k0 + 5u;
#undef TF_R
  o0 = x0; o1 = x1;
}

__device__ inline float erfinv_f(float x) { // XLA f32 ErfInv (Giles)
  float w = -log1pf(-x*x);
  float p;
  if (w < 5.0f) {
    w = w - 2.5f;
    p = 2.81022636e-08f;
    p = fmaf(p, w, 3.43273939e-07f);
    p = fmaf(p, w, -3.5233877e-06f);
    p = fmaf(p, w, -4.39150654e-06f);
    p = fmaf(p, w, 0.00021858087f);
    p = fmaf(p, w, -0.00125372503f);
    p = fmaf(p, w, -0.00417768164f);
    p = fmaf(p, w, 0.246640727f);
    p = fmaf(p, w, 1.50140941f);
  } else {
    w = sqrtf(w) - 3.0f;
    p = -0.000200214257f;
    p = fmaf(p, w, 0.000100950558f);
    p = fmaf(p, w, 0.00134934322f);
    p = fmaf(p, w, -0.00367342844f);
    p = fmaf(p, w, 0.00573950773f);
    p = fmaf(p, w, -0.0076224613f);
    p = fmaf(p, w, 0.00943887047f);
    p = fmaf(p, w, 1.00167406f);
    p = fmaf(p, w, 2.83297682f);
  }
  return p*x;
}
__device__ inline float normal_from_bits(unsigned bits) {
  float f = __uint_as_float((bits >> 9) | 0x3F800000u) - 1.0f;
  float x = fmaxf(-0.99999994f, fmaf(f, 1.99999994f, -0.99999994f));
  return 1.41421356237f * erfinv_f(x);
}

__device__ inline double mel_fpt(int j) {
  double mmax = 2595.0 * log10(1.0 + 8000.0/700.0);
  return 700.0 * (pow(10.0, (mmax * (double)j / 81.0) / 2595.0) - 1.0);
}

// ---------------- init ----------------
__global__ void k_init(float* W, const float* wih, const float* w0,
                       const float* w1, const float* w2, const float* vtw, const float* nfw,
                       const float* ir) {
  long id = (long)blockIdx.x*256 + threadIdx.x;
  if (id < R_WIN) {
    double w = 0.5 - 0.5*cos(2.0*M_PI*(double)id/1024.0);
    W[oWIN+id] = (float)w; return;
  } id -= R_WIN;
  if (id < R_TW) {
    double a = -2.0*M_PI*(double)id/1024.0;
    W[oTW+2*id] = (float)cos(a); W[oTW+2*id+1] = (float)sin(a); return;
  } id -= R_TW;
  if (id < R_TWF) {
    double a = -2.0*M_PI*(double)id/262144.0;
    W[oTWF+2*id] = (float)cos(a); W[oTWF+2*id+1] = (float)sin(a); return;
  } id -= R_TWF;
  if (id < R_TWC) {
    double a = -2.0*M_PI*(double)id/512.0;
    W[oTWC+2*id] = (float)cos(a); W[oTWC+2*id+1] = (float)sin(a); return;
  } id -= R_TWC;
  if (id < R_AW) {
    double fr = (double)id*(8000.0/512.0); double fsq = fr*fr;
    double num = 12194.217*12194.217*fsq*fsq;
    double den = (fsq+20.6*20.6)*(fsq+107.7*107.7)*(fsq+737.9*737.9)*sqrt(fsq+12194.217*12194.217) + 1e-8;
    W[oAW+id] = (float)(num/den); return;
  } id -= R_AW;
  if (id < R_MELFB) {
    int k = (int)(id/80), m = (int)(id%80);
    double fk = (double)k*(8000.0/512.0);
    double f0p = mel_fpt(m), f1p = mel_fpt(m+1), f2p = mel_fpt(m+2);
    double lower = (fk - f0p)/(f1p - f0p);
    double upper = (f2p - fk)/(f2p - f1p);
    double v = fmax(0.0, fmin(lower, upper));
    W[oMELFB+id] = (float)v; return;
  } id -= R_MELFB;
  if (id < R_WSQI) {
    int t = (int)id;
    int n1 = t/256; if (n1 > 625) n1 = 625;
    int n0t = t - 1023 + 255; int n0 = (n0t > 0) ? n0t/256 : 0;
    double s = 0.0;
    for (int n = n0; n <= n1; ++n) {
      int o = t - n*256;
      double wv = 0.5 - 0.5*cos(2.0*M_PI*(double)o/1024.0);
      s += wv*wv;
    }
    float sf = (float)s;
    W[oWSQI+t] = (sf > 1e-11f) ? (1.0f/sf) : 1.0f; return;
  } id -= R_WSQI;
  if (id < R_WIHT) { long k = id/768, g = id%768; W[oWIHT+id] = wih[g*80+k];  return; } id -= R_WIHT;
  if (id < R_W0T)  { long d = id/512, j = id%512; W[oW0T+id] = w0[j*21+d];   return; } id -= R_W0T;
  if (id < R_W1T)  { long k = id/512, j = id%512; W[oW1T+id] = w1[j*512+k];  return; } id -= R_W1T;
  if (id < R_W2T)  { long k = id/512, j = id%512; W[oW2T+id] = w2[j*512+k];  return; } id -= R_W2T;
  if (id < R_VTT)  { long k = id/65,  m = id%65;  W[oVTT+id] = vtw[m*512+k]; return; } id -= R_VTT;
  if (id < R_NFT)  { long k = id/65,  m = id%65;  W[oNFT+id] = nfw[m*512+k]; return; } id -= R_NFT;
  if (id < R_IR) {
    size_t base = oCONVA + 2*((size_t)8*NCONV + id);
    W[base] = (id < 8000) ? ir[id] : 0.0f; W[base+1] = 0.0f; return;
  }
}

__global__ void k_zacc(float* W) {
  size_t id = (size_t)blockIdx.x*256 + threadIdx.x;
  if (id < (size_t)BB*ACCLEN) W[oACC+id] = 0.0f;
}

// ---------------- f0: direct autocorrelation, float4-vectorized via 4 shifted copies ----------------
__global__ __launch_bounds__(320) void k_f0(const float* audio, float* W) {
  int blk = blockIdx.x; int b = blk/FRM, f = blk%FRM; int tid = threadIdx.x;
  __shared__ float fr4[4][1032];       // fr4[s][i] = fr[i+s] (0 beyond), rows 16B-aligned
  __shared__ float wpow[5];
  __shared__ float wmax[5];
  __shared__ int   wmaxi[5];
  const float* arow = audio + (size_t)b*TLEN;
  for (int idx = tid; idx < 4*1032; idx += 320) {
    int s = idx/1032, i = idx - s*1032;
    int j = i + s;
    fr4[s][i] = (j < 1024) ? arow[mirror_idx(f*256 + j - 512)] : 0.f;
  }
  __syncthreads();
  int lane = tid & 63, wv = tid >> 6;
  float p = 0.f;
  for (int i = tid; i < 1024; i += 320) { float x = fr4[0][i]; p += x*x; }
  for (int off = 32; off; off >>= 1) p += __shfl_down(p, off, 64);
  if (lane == 0) wpow[wv] = p;
  float vbest = -1e30f; int ibest = tid;
  if (tid < 304) {
    int lag = 16 + tid;
    int s = lag & 3, base = lag - s;
    int qmax = (1023 - lag) >> 2;
    float acc = 0.f;
    for (int q = 0; q <= qmax; ++q) {
      float4 u = *(const float4*)&fr4[0][4*q];
      float4 v = *(const float4*)&fr4[s][base + 4*q];
      acc += u.x*v.x + u.y*v.y + u.z*v.z + u.w*v.w;
    }
    vbest = acc;
  }
  for (int off = 32; off; off >>= 1) {
    float v2 = __shfl_down(vbest, off, 64);
    int i2 = __shfl_down(ibest, off, 64);
    if (v2 > vbest || (v2 == vbest && i2 < ibest)) { vbest = v2; ibest = i2; }
  }
  if (lane == 0) { wmax[wv] = vbest; wmaxi[wv] = ibest; }
  __syncthreads();
  if (tid == 0) {
    float ac0 = wpow[0]+wpow[1]+wpow[2]+wpow[3]+wpow[4];
    float bv = wmax[0]; int bi = wmaxi[0];
    #pragma unroll
    for (int q = 1; q < 5; ++q) {
      if (wmax[q] > bv || (wmax[q] == bv && wmaxi[q] < bi)) { bv = wmax[q]; bi = wmaxi[q]; }
    }
    float inv = 1.0f/(ac0 + 1e-8f);
    float best = bv*inv;
    float f0v = (best < 0.3f) ? 0.0f : (SRF/(float)(bi + 16));
    W[oF0 + blk] = f0v;
  }
}

// ---------------- STFT of audio + loud + mel ----------------
__global__ __launch_bounds__(256) void k_stft_mel(const float* audio, float* W) {
  int blk = blockIdx.x; int b = blk/FRM, f = blk%FRM; int tid = threadIdx.x;
  __shared__ float2 cb[1024];
  __shared__ float spec[513];
  __shared__ float redbuf[4];
  const float* arow = audio + (size_t)b*TLEN;
  const float2* tw = (const float2*)(W + oTW);
  for (int i = tid; i < 1024; i += 256) {
    float v = arow[mirror_idx(f*256 + i - 512)] * W[oWIN + i];
    int pos = __brev((unsigned)i) >> 22;
    cb[pos] = make_float2(v, 0.f);
  }
  __syncthreads();
  fft2<10,1>(cb, tw, tid, 256, false);
  for (int k = tid; k < 513; k += 256) { float2 z = cb[k]; spec[k] = z.x*z.x + z.y*z.y; }
  __syncthreads();
  float part = 0.f;
  for (int k = tid; k < 513; k += 256) part += (spec[k] + 1e-8f) * W[oAW + k];
  for (int off = 32; off; off >>= 1) part += __shfl_down(part, off, 64);
  if ((tid & 63) == 0) redbuf[tid >> 6] = part;
  __syncthreads();
  if (tid == 0) {
    float s = redbuf[0]+redbuf[1]+redbuf[2]+redbuf[3];
    W[oLOUD + blk] = 10.0f * log10f(s / 513.0f);
  }
  for (int m = tid; m < 80; m += 256) {
    float s = 0.f;
    for (int k = 0; k < 513; ++k) s += spec[k]*W[oMELFB + (size_t)k*80 + m];
    W[oMEL + (size_t)blk*80 + m] = logf(s + 1e-5f);
  }
}

// ---------------- mel normalization over time ----------------
__global__ void k_melnorm(float* W) {
  int id = blockIdx.x*256 + threadIdx.x;
  if (id >= BB*80) return;
  int b = id/80, m = id%80;
  double s = 0.0, ss = 0.0;
  for (int f = 0; f < FRM; ++f) {
    double v = W[oMEL + ((size_t)b*FRM + f)*80 + m];
    s += v; ss += v*v;
  }
  double mean = s/FRM;
  double var = ss/FRM - mean*mean;
  float mu = (float)mean;
  float rstd = (float)(1.0/sqrt(var + 1e-5));
  for (int f = 0; f < FRM; ++f) {
    size_t idx = oMEL + ((size_t)b*FRM + f)*80 + m;
    W[idx] = (W[idx] - mu)*rstd;
  }
}

// ---------------- GRU input precompute ----------------
__global__ void k_xp(float* W, const float* bih) {
  size_t id = (size_t)blockIdx.x*256 + threadIdx.x;
  if (id >= (size_t)NFRM*768) return;
  int g = (int)(id % 768);
  size_t q = id / 768;
  const float* mrow = W + oMEL + q*80;
  float acc = bih[g];
  for (int k = 0; k < 80; ++k) acc = fmaf(mrow[k], W[oWIHT + (size_t)k*768 + g], acc);
  W[oXP + q*768 + g] = acc;
}

// ---------------- persistent MFMA GRU: 1 block, 512 threads, all 8 batches ----------------
// Wave w owns output tiles 6w..6w+5. Tiles 0..4 in registers (bw[40]), tile 5 in LDS.
__global__ __launch_bounds__(512, 2) void k_gru_mfma(float* W, const float* whh, const float* bhh) {
  __shared__ unsigned short sB[32768];   // 64 KB: 128 lcols x 256
  __shared__ unsigned short sA[4096];    // 8 KB
  __shared__ float sGH[6144];            // 24 KB: [8][768]
  int tid = threadIdx.x;
  int w = tid >> 6, l = tid & 63;
  const float* XP = W + oXP;
  float* HS = W + oHS;

  for (int idx = tid; idx < 32768; idx += 512) {
    int lcol = idx >> 8, k = idx & 255;
    int gcol = 96*(lcol >> 4) + 80 + (lcol & 15);
    sB[lcol*256 + (k ^ ((lcol & 7) << 3))] = f2bf(whh[(size_t)gcol*256 + k]);
  }
  for (int idx = tid; idx < 4096; idx += 512) sA[idx] = 0;

  int cl = l & 15, khalf = (l >> 4) * 8;
  bf16x8 bw[40];
  #pragma unroll
  for (int t2 = 0; t2 < 5; ++t2) {
    int col = (6*w + t2)*16 + cl;
    #pragma unroll
    for (int kk = 0; kk < 8; ++kk) {
      const float* src = whh + (size_t)col*256 + kk*32 + khalf;
      short8 tmp;
      #pragma unroll
      for (int j = 0; j < 8; ++j) tmp[j] = (short)f2bf(src[j]);
      bw[t2*8 + kk] = __builtin_bit_cast(bf16x8, tmp);
    }
  }

  int g = tid & 255, bbase = tid >> 8;
  float bh_r = bhh[g], bh_z = bhh[256 + g], bh_n = bhh[512 + g];
  float hprev[4] = {0.f, 0.f, 0.f, 0.f};
  int aXor = (cl & 7) << 3;
  int lcol5 = w*16 + cl;

  __syncthreads();

#define LDA(kk) (*(const bf16x8*)&sA[(cl)*256 + (((kk)*32 + khalf) ^ aXor)])
#define LDB(kk) (*(const bf16x8*)&sB[(lcol5)*256 + (((kk)*32 + khalf) ^ aXor)])
#define STEPK(A_, kk) \
    c0 = MFMA_BF16(A_, bw[0*8+(kk)], c0, 0, 0, 0); \
    c1 = MFMA_BF16(A_, bw[1*8+(kk)], c1, 0, 0, 0); \
    c2 = MFMA_BF16(A_, bw[2*8+(kk)], c2, 0, 0, 0); \
    c3 = MFMA_BF16(A_, bw[3*8+(kk)], c3, 0, 0, 0); \
    c4 = MFMA_BF16(A_, bw[4*8+(kk)], c4, 0, 0, 0); \
    c5 = MFMA_BF16(A_, LDB(kk), c5, 0, 0, 0);

  for (int t = 0; t < FRM; ++t) {
    float xr[4], xz[4], xn[4];
    #pragma unroll
    for (int j = 0; j < 4; ++j) {
      const float* xpp = XP + ((size_t)(bbase + 2*j)*FRM + t)*768 + g;
      xr[j] = xpp[0]; xz[j] = xpp[256]; xn[j] = xpp[512];
    }
    f32x4 c0 = {0,0,0,0}, c1 = {0,0,0,0}, c2 = {0,0,0,0};
    f32x4 c3 = {0,0,0,0}, c4 = {0,0,0,0}, c5 = {0,0,0,0};
    bf16x8 a0 = LDA(0), a1 = LDA(1), a2 = LDA(2), a3 = LDA(3);
    STEPK(a0, 0) STEPK(a1, 1) STEPK(a2, 2) STEPK(a3, 3)
    a0 = LDA(4); a1 = LDA(5); a2 = LDA(6); a3 = LDA(7);
    STEPK(a0, 4) STEPK(a1, 5) STEPK(a2, 6) STEPK(a3, 7)
    int rowg = l >> 4;
    if (rowg < 2) {
      #pragma unroll
      for (int j = 0; j < 4; ++j) {
        int row = rowg*4 + j;
        sGH[row*768 + (6*w + 0)*16 + cl] = c0[j];
        sGH[row*768 + (6*w + 1)*16 + cl] = c1[j];
        sGH[row*768 + (6*w + 2)*16 + cl] = c2[j];
        sGH[row*768 + (6*w + 3)*16 + cl] = c3[j];
        sGH[row*768 + (6*w + 4)*16 + cl] = c4[j];
        sGH[row*768 + (6*w + 5)*16 + cl] = c5[j];
      }
    }
    __syncthreads();
    #pragma unroll
    for (int j = 0; j < 4; ++j) {
      int bb = bbase + 2*j;
      float ghr = sGH[bb*768 + g];
      float ghz = sGH[bb*768 + 256 + g];
      float ghn = sGH[bb*768 + 512 + g];
      float r = 1.0f/(1.0f + __expf(-(xr[j] + ghr + bh_r)));
      float z = 1.0f/(1.0f + __expf(-(xz[j] + ghz + bh_z)));
      float nn = tanh_fast(xn[j] + r*(ghn + bh_n));
      float h = (1.0f - z)*nn + z*hprev[j];
      hprev[j] = h;
      HS[((size_t)bb*FRM + t)*256 + g] = h;
      sA[bb*256 + (g ^ ((bb & 7) << 3))] = f2bf(h);
    }
    __syncthreads();
  }
#undef LDA
#undef LDB
#undef STEPK
}

// ---------------- projection ----------------
__global__ void k_proj(float* W, const float* projw, const float* projb) {
  size_t id = (size_t)blockIdx.x*256 + threadIdx.x;
  if (id >= (size_t)NFRM*16) return;
  int zi = (int)(id % 16);
  size_t q = id / 16;
  const float* hrow = W + oHS + q*256;
  float acc = projb[zi];
  for (int k = 0; k < 256; ++k) acc = fmaf(hrow[k], projw[zi*256 + k], acc);
  W[oZ + q*16 + zi] = acc;
}

// ---------------- MLP + heads ----------------
__device__ inline void ln_lrelu(float acc[8], float gj, float ej, float out[8][512],
                                float wred[8][8][2], float stat[8][2],
                                int tid, int lane, int wv, int j) {
  #pragma unroll
  for (int i = 0; i < 8; ++i) {
    float s = acc[i], ss = acc[i]*acc[i];
    for (int off = 32; off; off >>= 1) { s += __shfl_down(s, off, 64); ss += __shfl_down(ss, off, 64); }
    if (lane == 0) { wred[i][wv][0] = s; wred[i][wv][1] = ss; }
  }
  __syncthreads();
  if (tid < 8) {
    float s = 0.f, ss = 0.f;
    #pragma unroll
    for (int w = 0; w < 8; ++w) { s += wred[tid][w][0]; ss += wred[tid][w][1]; }
    float mean = s/512.0f;
    float var = ss/512.0f - mean*mean;
    stat[tid][0] = mean;
    stat[tid][1] = 1.0f/sqrtf(var + 1e-5f);
  }
  __syncthreads();
  #pragma unroll
  for (int i = 0; i < 8; ++i) {
    float v = (acc[i] - stat[i][0])*stat[i][1]*gj + ej;
    out[i][j] = (v >= 0.f) ? v : 0.1f*v;
  }
}

__global__ __launch_bounds__(512) void k_mlp(float* W, const float* gender, const float* age,
    const float* b0, const float* g0, const float* e0,
    const float* b1, const float* g1, const float* e1,
    const float* b2, const float* g2, const float* e2,
    const float* oqw, const float* oqb, const float* vtb, const float* nfb) {
  __shared__ float in0[8][21];
  __shared__ float actA[8][512];
  __shared__ float actB[8][512];
  __shared__ float wred[8][8][2];
  __shared__ float stat[8][2];
  int tid = threadIdx.x; int q0 = blockIdx.x*8;
  if (tid < 168) {
    int i = tid/21, d = tid%21; int q = q0 + i; int b = q/FRM;
    float v;
    if (d < 16) v = W[oZ + (size_t)q*16 + d];
    else if (d == 16) v = (logf(W[oF0 + q] + 1e-5f) - 4.0f)*0.25f;
    else if (d == 17) v = W[oLOUD + q]/100.0f + 1.0f;
    else if (d == 18) v = gender[b*2];
    else if (d == 19) v = gender[b*2 + 1];
    else v = age[b];
    in0[i][d] = v;
  }
  __syncthreads();
  int j = tid, lane = tid & 63, wv = tid >> 6;
  float acc[8];
  #pragma unroll
  for (int i = 0; i < 8; ++i) acc[i] = b0[j];
  for (int d = 0; d < 21; ++d) {
    float w = W[oW0T + (size_t)d*512 + j];
    #pragma unroll
    for (int i = 0; i < 8; ++i) acc[i] = fmaf(in0[i][d], w, acc[i]);
  }
  ln_lrelu(acc, g0[j], e0[j], actA, wred, stat, tid, lane, wv, j);
  __syncthreads();
  #pragma unroll
  for (int i = 0; i < 8; ++i) acc[i] = b1[j];
  for (int k = 0; k < 512; ++k) {
    float w = W[oW1T + (size_t)k*512 + j];
    #pragma unroll
    for (int i = 0; i < 8; ++i) acc[i] = fmaf(actA[i][k], w, acc[i]);
  }
  ln_lrelu(acc, g1[j], e1[j], actB, wred, stat, tid, lane, wv, j);
  __syncthreads();
  #pragma unroll
  for (int i = 0; i < 8; ++i) acc[i] = b2[j];
  for (int k = 0; k < 512; ++k) {
    float w = W[oW2T + (size_t)k*512 + j];
    #pragma unroll
    for (int i = 0; i < 8; ++i) acc[i] = fmaf(actB[i][k], w, acc[i]);
  }
  ln_lrelu(acc, g2[j], e2[j], actA, wred, stat, tid, lane, wv, j);
  __syncthreads();
  for (int x = tid; x < 520; x += 512) {
    int i = x/65, m = x%65;
    float a = vtb[m], a2 = nfb[m];
    for (int k = 0; k < 512; ++k) {
      float h = actA[i][k];
      a  = fmaf(h, W[oVTT + (size_t)k*65 + m], a);
      a2 = fmaf(h, W[oNFT + (size_t)k*65 + m], a2);
    }
    W[oVT + (size_t)(q0+i)*65 + m] = sigm(a);
    W[oNF + (size_t)(q0+i)*65 + m] = sigm(a2);
  }
  if (tid < 8) {
    float a = oqb[0];
    for (int k = 0; k < 512; ++k) a = fmaf(actA[tid][k], oqw[k], a);
    W[oOQ + q0 + tid] = sigm(a);
  }
}

// ---------------- noise: JAX threefry partitionable, key (0,42), bits = o0^o1 ----------------
__global__ void k_noise(float* W) {
  int p = blockIdx.x*256 + threadIdx.x;
  if (p >= BB*TLEN) return;
  unsigned o0, o1;
  threefry2x32(0u, 42u, 0u, (unsigned)p, o0, o1);
  W[oNOISE + p] = normal_from_bits(o0 ^ o1);
}

// ---------------- glottal: 4 samples/thread, 157 chunks ----------------
__global__ __launch_bounds__(256) void k_glottal(float* W) {
  int b = blockIdx.x; int tid = threadIdx.x;
  __shared__ float wsums[4];
  __shared__ float lastg[256];
  __shared__ double carry_sh;
  __shared__ float gprev_sh, ctot_sh;
  const float* f0r = W + oF0 + (size_t)b*FRM;
  const float* oqr = W + oOQ + (size_t)b*FRM;
  float* grow = W + oGLOT + (size_t)b*TLEN;
  if (tid == 0) { carry_sh = 0.0; gprev_sh = 0.f; }
  __syncthreads();
  int lane = tid & 63, wv = tid >> 6;
  for (int c = 0; c < 157; ++c) {
    int i0 = c*1024 + tid*4;
    float v[4]; float sum4 = 0.f;
    #pragma unroll
    for (int j = 0; j < 4; ++j) {
      int i = i0 + j;
      float x = (i < TLEN) ? interpF(f0r, i)*(1.0f/SRF) : 0.f;
      v[j] = x; sum4 += x;
    }
    float s = sum4;
    #pragma unroll
    for (int off = 1; off < 64; off <<= 1) {
      float o = __shfl_up(s, off, 64);
      if (lane >= off) s += o;
    }
    if (lane == 63) wsums[wv] = s;
    __syncthreads();
    float wpre = 0.f;
    for (int ww = 0; ww < wv; ++ww) wpre += wsums[ww];
    double ph0 = carry_sh + (double)(wpre + s - sum4);
    float run = 0.f; float gq[4];
    #pragma unroll
    for (int j = 0; j < 4; ++j) {
      int i = i0 + j;
      run += v[j];
      float ph = (float)(ph0 + (double)run);
      float p = ph - floorf(ph);
      float oqu = interpF(oqr, i);
      float oqc = fminf(fmaxf(oqu, 0.1f), 0.9f);
      float pulse = 0.5f*(1.0f - cosf(3.14159265358979f * p / (oqc + 1e-8f)));
      float gs = 1.0f/(1.0f + __expf(-(oqc - p)*100.0f));
      gq[j] = pulse*gs;
    }
    lastg[tid] = gq[3];
    if (tid == 255) ctot_sh = wpre + s;
    __syncthreads();
    float prevg = (tid == 0) ? gprev_sh : lastg[tid-1];
    #pragma unroll
    for (int j = 0; j < 4; ++j) {
      int i = i0 + j;
      if (i < TLEN) {
        float gl = (j == 0) ? prevg : gq[j-1];
        grow[i] = (i == 0) ? 0.f : (gq[j] - gl);
      }
    }
    __syncthreads();
    if (tid == 0) { carry_sh += (double)ctot_sh; gprev_sh = lastg[255]; }
  }
}

// ---------------- fused STFT->filter->ISTFT OLA ----------------
__global__ __launch_bounds__(256) void k_filtsynth(float* W) {
  int blk = blockIdx.x; int b = blk/FRM, f = blk%FRM; int tid = threadIdx.x;
  __shared__ float2 cG[1024], cN[1024];
  __shared__ float fvt[65], fnf[65];
  const float* grow = W + oGLOT + (size_t)b*TLEN;
  const float* nrow = W + oNOISE + (size_t)b*TLEN;
  const float2* tw = (const float2*)(W + oTW);
  for (int i = tid; i < 1024; i += 256) {
    int si = mirror_idx(f*256 + i - 512);
    float wv = W[oWIN + i];
    int pos = __brev((unsigned)i) >> 22;
    cG[pos] = make_float2(grow[si]*wv, 0.f);
    cN[pos] = make_float2(nrow[si]*wv, 0.f);
  }
  if (tid < 65) {
    fvt[tid] = W[oVT + ((size_t)b*FRM + f)*65 + tid];
    fnf[tid] = W[oNF + ((size_t)b*FRM + f)*65 + tid];
  }
  __syncthreads();
  fft2<10,1>(cG, tw, tid, 256, false);
  fft2<10,1>(cN, tw, tid, 256, false);
  for (int k = tid; k < 1024; k += 256) {
    int kp = min(k, 1024 - k);
    float fv = interp65(fvt, kp);
    float fn = interp65(fnf, kp);
    float2 zg = cG[k], zn = cN[k];
    cG[k] = make_float2(zg.x*fv + zn.x*fn, zg.y*fv + zn.y*fn);
  }
  __syncthreads();
  for (int i = tid; i < 1024; i += 256) {
    int jj = __brev((unsigned)i) >> 22;
    if (jj > i) { float2 t2 = cG[i]; cG[i] = cG[jj]; cG[jj] = t2; }
  }
  __syncthreads();
  fft2<10,1>(cG, tw, tid, 256, true);
  float* arow = W + oACC + (size_t)b*ACCLEN + (size_t)f*256;
  for (int i = tid; i < 1024; i += 256) {
    float xv = cG[i].x*(1.0f/1024.0f)*W[oWIN + i];
    atomicAdd(arow + i, xv);
  }
}

// ---------------- dry ----------------
__global__ void k_dry(float* W, float* dout) {
  size_t id = (size_t)blockIdx.x*256 + threadIdx.x;
  if (id >= (size_t)BB*NCONV) return;
  int b = (int)(id / NCONV);
  int n = (int)(id % NCONV);
  float dv = 0.f;
  if (n < TLEN) {
    float val = W[oACC + (size_t)b*ACCLEN + 512 + n] * W[oWSQI + 512 + n];
    const float* lrow = W + oLOUD + (size_t)b*FRM;
    float pos = ((float)n + 0.5f) * (626.0f/160000.0f) - 0.5f;
    pos = fminf(fmaxf(pos, 0.0f), 625.0f);
    int lo = (int)floorf(pos);
    int hi = min(lo + 1, 625);
    float w = pos - (float)lo;
    float a0 = exp10f(lrow[lo]*0.05f);
    float a1 = exp10f(lrow[hi]*0.05f);
    float ampu = a0*(1.0f - w) + a1*w;
    dv = val*ampu;
    dout[(size_t)BB*TLEN + (size_t)b*TLEN + n] = dv;
  }
  ((float2*)(W + oCONVA))[id] = make_float2(dv, 0.f);
}

// ---------------- four-step FFT (N = 512*512) ----------------
__global__ __launch_bounds__(256) void k_conv_f1(const float* in, float* out,
                                                 const float* tw, const float* twf,
                                                 const float* twc) {
  int blk = blockIdx.x; int t = blk >> 9; int bcol = blk & 511; int tid = threadIdx.x;
  __shared__ float2 cb[512];
  const float2* src = (const float2*)in + (size_t)t*NCONV;
  for (int a = tid; a < 512; a += 256) {
    int pos = __brev((unsigned)a) >> 23;
    cb[pos] = src[(size_t)a*512 + bcol];
  }
  __syncthreads();
  fft2<9,2>(cb, (const float2*)tw, tid, 256, false);
  float2* dst = (float2*)out + (size_t)t*NCONV + (size_t)bcol*512;
  for (int k1 = tid; k1 < 512; k1 += 256) {
    unsigned m = (unsigned)bcol * (unsigned)k1;   // < 262144
    // twiddle = exp(-2pi i m/262144) = Tc[m>>9] (per 512) * Tf[m&511] (per 262144)
    float2 tc = ((const float2*)twc)[m >> 9];
    float2 tf = ((const float2*)twf)[m & 511];
    float wr = tc.x*tf.x - tc.y*tf.y;
    float wi = tc.x*tf.y + tc.y*tf.x;
    float2 v = cb[k1];
    dst[k1] = make_float2(v.x*wr - v.y*wi, v.x*wi + v.y*wr);
  }
}

__global__ __launch_bounds__(256) void k_conv_f2(const float* in, float* out, const float* tw) {
  int blk = blockIdx.x; int t = blk >> 9; int k1 = blk & 511; int tid = threadIdx.x;
  __shared__ float2 cb[512];
  const float2* src = (const float2*)in + (size_t)t*NCONV;
  for (int bb2 = tid; bb2 < 512; bb2 += 256) {
    int pos = __brev((unsigned)bb2) >> 23;
    cb[pos] = src[(size_t)bb2*512 + k1];
  }
  __syncthreads();
  fft2<9,2>(cb, (const float2*)tw, tid, 256, false);
  float2* dst = (float2*)out + (size_t)t*NCONV;
  for (int k2 = tid; k2 < 512; k2 += 256) {
    dst[(size_t)k1 + 512*(size_t)k2] = cb[k2];
  }
}

__global__ void k_mul(float* W) {
  size_t id = (size_t)blockIdx.x*256 + threadIdx.x;
  if (id >= (size_t)BB*NCONV) return;
  size_t k = id % NCONV;
  float2* A = (float2*)(W + oCONVA);
  float2 a = A[id];
  float2 c = A[(size_t)8*NCONV + k];
  float pr = a.x*c.x - a.y*c.y;
  float pi = a.x*c.y + a.y*c.x;
  A[id] = make_float2(pr, -pi);   // conjugate for inverse-via-forward
}

__global__ void k_wet(const float* W, float* dout) {
  size_t id = (size_t)blockIdx.x*256 + threadIdx.x;
  if (id >= (size_t)BB*TLEN) return;
  size_t b = id / TLEN, n = id % TLEN;
  dout[id] = ((const float2*)(W + oCONVA))[b*NCONV + n].x * (1.0f/262144.0f);
}

// ---------------- launch ----------------
extern "C" void kernel_launch(void* const* d_in, const int* in_sizes, int n_in,
                              void* d_out, int out_size, void* d_ws, size_t ws_size,
                              hipStream_t stream) {
  (void)in_sizes; (void)n_in; (void)out_size; (void)ws_size;
  const float* audio  = (const float*)d_in[0];
  const float* gender = (const float*)d_in[1];
  const float* age    = (const float*)d_in[2];
  const float* wih    = (const float*)d_in[3];
  const float* whh    = (const float*)d_in[4];
  const float* bih    = (const float*)d_in[5];
  const float* bhh    = (const float*)d_in[6];
  const float* projw  = (const float*)d_in[7];
  const float* projb  = (const float*)d_in[8];
  const float* w0     = (const float*)d_in[9];
  const float* b0     = (const float*)d_in[10];
  const float* g0     = (const float*)d_in[11];
  const float* e0     = (const float*)d_in[12];
  const float* w1     = (const float*)d_in[13];
  const float* b1     = (const float*)d_in[14];
  const float* g1     = (const float*)d_in[15];
  const float* e1     = (const float*)d_in[16];
  const float* w2     = (const float*)d_in[17];
  const float* b2     = (const float*)d_in[18];
  const float* g2     = (const float*)d_in[19];
  const float* e2     = (const float*)d_in[20];
  const float* oqw    = (const float*)d_in[21];
  const float* oqb    = (const float*)d_in[22];
  const float* vtw    = (const float*)d_in[23];
  const float* vtb    = (const float*)d_in[24];
  const float* nfw    = (const float*)d_in[25];
  const float* nfb    = (const float*)d_in[26];
  const float* ir     = (const float*)d_in[27];
  float* W = (float*)d_ws;
  float* dout = (float*)d_out;

  k_init<<<(int)((INIT_TOTAL + 255)/256), 256, 0, stream>>>(W, wih, w0, w1, w2, vtw, nfw, ir);
  k_f0<<<NFRM, 320, 0, stream>>>(audio, W);
  k_stft_mel<<<NFRM, 256, 0, stream>>>(audio, W);
  k_melnorm<<<3, 256, 0, stream>>>(W);
  k_xp<<<(int)(((size_t)NFRM*768 + 255)/256), 256, 0, stream>>>(W, bih);
  k_gru_mfma<<<1, 512, 0, stream>>>(W, whh, bhh);
  k_proj<<<(int)(((size_t)NFRM*16 + 255)/256), 256, 0, stream>>>(W, projw, projb);
  k_mlp<<<NFRM/8, 512, 0, stream>>>(W, gender, age, b0, g0, e0, b1, g1, e1, b2, g2, e2, oqw, oqb, vtb, nfb);
  k_zacc<<<(int)(((size_t)BB*ACCLEN + 255)/256), 256, 0, stream>>>(W);
  k_noise<<<(BB*TLEN + 255)/256, 256, 0, stream>>>(W);
  k_glottal<<<BB, 256, 0, stream>>>(W);
  k_filtsynth<<<NFRM, 256, 0, stream>>>(W);
  k_dry<<<(int)(((size_t)BB*NCONV + 255)/256), 256, 0, stream>>>(W, dout);
  k_conv_f1<<<9*512, 256, 0, stream>>>(W + oCONVA, W + oCONVB, W + oTW, W + oTWF, W + oTWC);
  k_conv_f2<<<9*512, 256, 0, stream>>>(W + oCONVB, W + oCONVA, W + oTW);
  k_mul<<<(int)(((size_t)BB*NCONV + 255)/256), 256, 0, stream>>>(W);
  k_conv_f1<<<8*512, 256, 0, stream>>>(W + oCONVA, W + oCONVB, W + oTW, W + oTWF, W + oTWC);
  k_conv_f2<<<8*512, 256, 0, stream>>>(W + oCONVB, W + oCONVA, W + oTW);
  k_wet<<<(int)(((size_t)BB*TLEN + 255)/256), 256, 0, stream>>>(W, dout);
}